// Round 1
// baseline (247.262 us; speedup 1.0000x reference)
//
#include <hip/hip_runtime.h>
#include <cstddef>

#define EPSF 1e-12f
#define NCB 90
#define NT 30
#define ODIM 256
#define DDIM 8192

typedef unsigned short u16;
typedef __attribute__((ext_vector_type(8))) short short8;
typedef __attribute__((ext_vector_type(4))) float float4v;

__device__ inline u16 f2bf(float f) {
  union { float f; unsigned u; } v; v.f = f;
  unsigned r = v.u + 0x7FFFu + ((v.u >> 16) & 1u);
  return (u16)(r >> 16);
}
__device__ inline float bf2f(u16 h) {
  union { unsigned u; float f; } v; v.u = ((unsigned)h) << 16;
  return v.f;
}

// ---------------------------------------------------------------------------
// K1 (MFMA): R9 structure + register-prefetch pipeline + NEW c-split x2:
// each block computes full logits+softmax (cheap, VALU was 13% busy) but only
// half of P's channel tiles. Grid 720->1440 (2.8->5.6 blocks/CU) to fix the
// latency-bound profile (MfmaUtil 3.6 / VALUBusy 13 / Occ 22). P layout and
// K2 are unchanged; math is bit-identical.
// ---------------------------------------------------------------------------
__global__ __launch_bounds__(256, 4) void k1_assign(
    const float* __restrict__ x,       // [8][128][16][900]
    const float* __restrict__ conv_w,  // [64][128]
    const float* __restrict__ conv_b,  // [64]
    float* __restrict__ P,             // [8][90][64][128]
    float* __restrict__ PA)            // [8][90][64]
{
  __shared__ u16 xtf[4160];        // logits A-frags: F*520 + lane*8 + j
  __shared__ u16 xf[2560];         // P B-frags (half): ct*640 + (lane>>4)*160 + (lane&15)*8 + j
  __shared__ float As[64 * 33];    // logits -> exp
  __shared__ u16 afr[2048];        // a frags
  __shared__ float invs[32];       // 1/sum per column
  __shared__ float pasum[256];

  const int bx0 = blockIdx.x;      // [0,1440)
  const int n = bx0 & 7;           // XCD pin: n = bx0&7 (twins share XCD L2)
  const int r2 = bx0 >> 3;         // [0,180)
  const int cb = r2 >> 1;
  const int chb = r2 & 1;          // channel half for P
  const int t = threadIdx.x;
  const int lane = t & 63;
  const int w = t >> 6;            // wave 0..3

  const float* xn = x + (size_t)n * 1843200 + cb * 10;

  const int colt = w & 1;
  const int kt0 = w >> 1;
  const float bk0 = conv_b[kt0 * 16 + (lane & 15)];
  const float bk1 = conv_b[(kt0 + 2) * 16 + (lane & 15)];

  short8 w0h[4], w0l[4], w1h[4], w1l[4];
  {
    int kr0 = kt0 * 16 + (lane & 15);
    int kr1 = kr0 + 32;
    int cbase = (lane >> 4) << 3;
#pragma unroll
    for (int cb32 = 0; cb32 < 4; ++cb32) {
      const float* wp0 = conv_w + (size_t)kr0 * 128 + cb32 * 32 + cbase;
      const float* wp1 = conv_w + (size_t)kr1 * 128 + cb32 * 32 + cbase;
      union { u16 u[8]; short8 v; } hh, ll;
#pragma unroll
      for (int j = 0; j < 8; ++j) {
        float fv = wp0[j];
        u16 h = f2bf(fv);
        hh.u[j] = h;
        ll.u[j] = f2bf(fv - bf2f(h));
      }
      w0h[cb32] = hh.v; w0l[cb32] = ll.v;
#pragma unroll
      for (int j = 0; j < 8; ++j) {
        float fv = wp1[j];
        u16 h = f2bf(fv);
        hh.u[j] = h;
        ll.u[j] = f2bf(fv - bf2f(h));
      }
      w1h[cb32] = hh.v; w1l[cb32] = ll.v;
    }
  }

  float4v pacc[4];
#pragma unroll
  for (int i = 0; i < 4; ++i) pacc[i] = (float4v){0.f, 0.f, 0.f, 0.f};
  float pak = 0.f;

  // ---- prologue: load cc=0 x into registers ----
  float2 xr[8];
#pragma unroll
  for (int s = 0; s < 8; ++s) {
    int e2 = t + 256 * s;
    int c = e2 >> 4, p = e2 & 15;
    int cl = 2 * p;
    int h = cl / 10, wi = cl - 10 * h;
    xr[s] = *(const float2*)(xn + (size_t)c * 14400 + h * 900 + wi);
  }

  for (int cc = 0; cc < 5; ++cc) {
    __syncthreads();                     // prev P-mfma done before restaging
    // ---- write prefetched regs to both LDS layouts ----
    // xf (P B-frags) only for this block's channel half: c>>6 == s>>2 == chb
#pragma unroll
    for (int s = 0; s < 8; ++s) {
      int e2 = t + 256 * s;
      int c = e2 >> 4, p = e2 & 15;
      int cl = 2 * p;
      u16 h0 = f2bf(xr[s].x), h1 = f2bf(xr[s].y);
      if ((s >> 2) == chb) {
        int ip = ((c >> 4) & 3) * 640 + (p >> 2) * 160 + (c & 15) * 8 + (cl & 7);
        ushort2 pr; pr.x = h0; pr.y = h1;
        *(ushort2*)&xf[ip] = pr;
      }
      int F = (p >> 3) * 4 + (c >> 5);
      int L = (((c >> 3) & 3) << 4) + (cl & 15);
      int i0 = F * 520 + L * 8 + (c & 7);
      xtf[i0] = h0;
      xtf[i0 + 8] = h1;
    }
    // ---- issue next cc's loads; they retire behind this cc's compute ----
    if (cc < 4) {
#pragma unroll
      for (int s = 0; s < 8; ++s) {
        int e2 = t + 256 * s;
        int c = e2 >> 4, p = e2 & 15;
        int g = (cc + 1) * 32 + 2 * p;
        int h = g / 10, wi = g - 10 * h;
        xr[s] = *(const float2*)(xn + (size_t)c * 14400 + h * 900 + wi);
      }
    }
    __syncthreads();

    // ---- logits MFMA ----
    {
      float4v d0 = (float4v){0.f, 0.f, 0.f, 0.f};
      float4v d1 = (float4v){0.f, 0.f, 0.f, 0.f};
#pragma unroll
      for (int cb32 = 0; cb32 < 4; ++cb32) {
        short8 xa = *(short8*)&xtf[(colt * 4 + cb32) * 520 + lane * 8];
        d0 = __builtin_amdgcn_mfma_f32_16x16x32_bf16(xa, w0h[cb32], d0, 0, 0, 0);
        d0 = __builtin_amdgcn_mfma_f32_16x16x32_bf16(xa, w0l[cb32], d0, 0, 0, 0);
        d1 = __builtin_amdgcn_mfma_f32_16x16x32_bf16(xa, w1h[cb32], d1, 0, 0, 0);
        d1 = __builtin_amdgcn_mfma_f32_16x16x32_bf16(xa, w1l[cb32], d1, 0, 0, 0);
      }
      int colb = colt * 16 + ((lane >> 4) << 2);
      int kr0 = kt0 * 16 + (lane & 15);
      int kr1 = kr0 + 32;
#pragma unroll
      for (int r = 0; r < 4; ++r) {
        As[kr0 * 33 + colb + r] = d0[r] + bk0;
        As[kr1 * 33 + colb + r] = d1[r] + bk1;
      }
    }
    __syncthreads();

    // ---- wave-local softmax over k for cols [8w, 8w+8) ----
    {
      const int col8 = lane & 7;
      const int kq = lane >> 3;
      const int colg = w * 8 + col8;
      float m = -3.4e38f;
#pragma unroll
      for (int i = 0; i < 8; ++i) m = fmaxf(m, As[(kq * 8 + i) * 33 + colg]);
      m = fmaxf(m, __shfl_xor(m, 8));
      m = fmaxf(m, __shfl_xor(m, 16));
      m = fmaxf(m, __shfl_xor(m, 32));
      float s = 0.f;
#pragma unroll
      for (int i = 0; i < 8; ++i) {
        int a = (kq * 8 + i) * 33 + colg;
        float e = __expf(As[a] - m);
        As[a] = e;
        s += e;
      }
      s += __shfl_xor(s, 8);
      s += __shfl_xor(s, 16);
      s += __shfl_xor(s, 32);
      if (kq == 0) invs[w * 8 + col8] = 1.f / s;
    }
    // ---- a-frag build (same wave, no barrier needed) ----
    {
      union { u16 u[8]; short8 v; } cvt;
      float paks = 0.f;
#pragma unroll
      for (int j = 0; j < 8; ++j) {
        float a = As[lane * 33 + w * 8 + j] * invs[w * 8 + j];
        paks += a;
        cvt.u[j] = f2bf(a);
      }
      pak += paks;
      int dst = ((lane >> 4) * 64 + (w << 4) + (lane & 15)) * 8;
      *(short8*)&afr[dst] = cvt.v;
    }
    __syncthreads();

    // ---- P MFMA: wave w owns kt = w; 4 c-tiles (this block's half) ----
    {
      short8 aa = *(short8*)&afr[(w * 64 + lane) * 8];
#pragma unroll
      for (int ct = 0; ct < 4; ++ct) {
        short8 xb = *(short8*)&xf[ct * 640 + (lane >> 4) * 160 + (lane & 15) * 8];
        pacc[ct] = __builtin_amdgcn_mfma_f32_16x16x32_bf16(aa, xb, pacc[ct], 0, 0, 0);
      }
    }
  }

  float* Pp = P + (size_t)(n * NCB + cb) * DDIM;
  {
    int krow = w * 16 + ((lane >> 4) << 2);
    int c0 = lane & 15;
#pragma unroll
    for (int ct = 0; ct < 4; ++ct)
#pragma unroll
      for (int r = 0; r < 4; ++r)
        Pp[(krow + r) * 128 + chb * 64 + ct * 16 + c0] = pacc[ct][r];
  }
  if (chb == 0) {                  // block-uniform: PA written once per (n,cb)
    pasum[t] = pak;
    __syncthreads();
    if (t < 64)
      PA[(size_t)(n * NCB + cb) * 64 + t] =
          pasum[t] + pasum[64 + t] + pasum[128 + t] + pasum[192 + t];
  }
}

// ---------------------------------------------------------------------------
// K2: window-outer direct sums + XCD pin; bf16 vlad out. (unchanged)
// ---------------------------------------------------------------------------
__global__ __launch_bounds__(256) void k2_vlad(
    const float* __restrict__ P, const float* __restrict__ PA,
    const float* __restrict__ centers, u16* __restrict__ vlad16,
    float* __restrict__ gss)
{
  __shared__ float Ak[16];
  __shared__ float red[4];
  const int bx0 = blockIdx.x;                    // [0,960)
  const int id = (bx0 & 7) * 120 + (bx0 >> 3);   // XCD pin: n = bx0&7
  const int n = id / 120;
  const int rem = id - n * 120;
  const int wt = rem >> 2, eb = rem & 3;
  const int win = n * NT + wt;
  const int t = threadIdx.x;

  if (t < 64) {
    int kk = t >> 2, ii = t & 3;
    float s = 0.f;
#pragma unroll
    for (int ss = 0; ss < 5; ++ss) {
      int i = ii + 4 * ss;
      int cb = (3 * wt + 80 + i) % 90;
      s += PA[((size_t)n * NCB + cb) * 64 + eb * 16 + kk];
    }
    s += __shfl_xor(s, 1);
    s += __shfl_xor(s, 2);
    if (ii == 0) Ak[kk] = s;
  }
  __syncthreads();

  const int e0 = eb * 2048 + t * 8;
  float v[8];
#pragma unroll
  for (int j = 0; j < 8; ++j) v[j] = 0.f;
#pragma unroll 5
  for (int i = 0; i < 20; ++i) {
    int cb = (3 * wt + 80 + i) % 90;
    const float* Pp = P + ((size_t)n * NCB + cb) * DDIM + e0;
    float4 u0 = *(const float4*)Pp;
    float4 u1 = *(const float4*)(Pp + 4);
    v[0] += u0.x; v[1] += u0.y; v[2] += u0.z; v[3] += u0.w;
    v[4] += u1.x; v[5] += u1.y; v[6] += u1.z; v[7] += u1.w;
  }
  const float A = Ak[t >> 4];
  const float* ce = centers + e0;
  float ss8 = 0.f;
#pragma unroll
  for (int j = 0; j < 8; ++j) {
    float val = v[j] - ce[j] * A;
    v[j] = val;
    ss8 += val * val;
  }
  float ssg = ss8;
  ssg += __shfl_xor(ssg, 1);
  ssg += __shfl_xor(ssg, 2);
  ssg += __shfl_xor(ssg, 4);
  ssg += __shfl_xor(ssg, 8);
  float rn = 1.f / fmaxf(sqrtf(ssg), EPSF);
  float ts = ss8 * rn * rn;
  ts += __shfl_xor(ts, 1);
  ts += __shfl_xor(ts, 2);
  ts += __shfl_xor(ts, 4);
  ts += __shfl_xor(ts, 8);
  ts += __shfl_xor(ts, 16);
  ts += __shfl_xor(ts, 32);
  if ((t & 63) == 0) red[t >> 6] = ts;
  __syncthreads();
  if (t == 0) gss[(size_t)win * 4 + eb] = red[0] + red[1] + red[2] + red[3];

  union { u16 u[8]; short8 s; } o;
#pragma unroll
  for (int j = 0; j < 8; ++j) o.u[j] = f2bf(v[j] * rn);
  *(short8*)(vlad16 + (size_t)win * DDIM + e0) = o.s;
}

// ---------------------------------------------------------------------------
// K0 (NEW): one-time mlp_w f32 -> bf16 cast. Bit-identical to what k3 did
// per-use; halves k3's w bytes (125->62 MB of re-reads) and kills its f2bf
// VALU. Runs after k2 so wbf can overlay the dead P region (no extra ws).
// ---------------------------------------------------------------------------
__global__ __launch_bounds__(256) void k0_wcast(
    const float* __restrict__ mlp_w, u16* __restrict__ wbf)
{
  const size_t i = (size_t)(blockIdx.x * 256 + threadIdx.x) * 8;
  float4 u0 = *(const float4*)(mlp_w + i);
  float4 u1 = *(const float4*)(mlp_w + i + 4);
  union { u16 u[8]; short8 s; } o;
  o.u[0] = f2bf(u0.x); o.u[1] = f2bf(u0.y); o.u[2] = f2bf(u0.z); o.u[3] = f2bf(u0.w);
  o.u[4] = f2bf(u1.x); o.u[5] = f2bf(u1.y); o.u[6] = f2bf(u1.z); o.u[7] = f2bf(u1.w);
  *(short8*)(wbf + i) = o.s;
}

// ---------------------------------------------------------------------------
// K3 (MFMA): bf16 weights + XCD pin on h so the 15 rt-blocks sharing one
// 64 KB w-slice all hit the same XCD's L2 (w no longer streams from L3).
// part[ks][240][256] = (vlad16 @ wbf^T) * ga[r].
// ---------------------------------------------------------------------------
__global__ __launch_bounds__(256) void k3_gemm(
    const u16* __restrict__ vlad16, const float* __restrict__ gss,
    const u16* __restrict__ wbf, float* __restrict__ part)
{
  __shared__ float ga[16];
  const int bx = blockIdx.x;       // [0,960)
  const int xcd = bx & 7;
  const int i6 = bx >> 3;          // [0,120)
  const int h = xcd * 8 + (i6 & 7);  // [0,64): same h -> same XCD
  const int rt = i6 >> 3;          // [0,15)
  const int ot = h & 1;            // o half
  const int ks = h >> 1;           // 0..31, K-slice of 256
  const int t = threadIdx.x;
  const int lane = t & 63;
  const int w = t >> 6;

  if (t < 16) {
    int r = rt * 16 + t;
    float s = gss[r * 4] + gss[r * 4 + 1] + gss[r * 4 + 2] + gss[r * 4 + 3];
    ga[t] = 1.f / fmaxf(sqrtf(s), EPSF);
  }
  __syncthreads();

  const int m = lane & 15;
  const int kg = lane >> 4;
  const int d0 = ks * 256 + kg * 8;
  const u16* arow = vlad16 + (size_t)(rt * 16 + m) * DDIM + d0;

  float4v acc[2];
#pragma unroll
  for (int i = 0; i < 2; ++i) acc[i] = (float4v){0.f, 0.f, 0.f, 0.f};

#pragma unroll
  for (int ko = 0; ko < 8; ++ko) {
    short8 a = *(const short8*)(arow + ko * 32);
#pragma unroll
    for (int nt = 0; nt < 2; ++nt) {
      int o = ot * 128 + w * 32 + nt * 16 + m;
      short8 bv = *(const short8*)(wbf + (size_t)o * DDIM + d0 + ko * 32);
      acc[nt] = __builtin_amdgcn_mfma_f32_16x16x32_bf16(a, bv, acc[nt], 0, 0, 0);
    }
  }

  float g4[4];
#pragma unroll
  for (int r = 0; r < 4; ++r) g4[r] = ga[kg * 4 + r];
  float* pp = part + ((size_t)ks * 240 + rt * 16) * ODIM;
#pragma unroll
  for (int nt = 0; nt < 2; ++nt) {
    int o = ot * 128 + w * 32 + nt * 16 + m;
#pragma unroll
    for (int r = 0; r < 4; ++r)
      pp[(kg * 4 + r) * ODIM + o] = acc[nt][r] * g4[r];
  }
}

// ---------------------------------------------------------------------------
// K4: sum 32 split-K partials + bias, row-normalize 240 x 256 (unchanged)
// ---------------------------------------------------------------------------
__global__ __launch_bounds__(256) void k4_out(
    const float* __restrict__ part, const float* __restrict__ bias,
    float* __restrict__ out)
{
  __shared__ float red[4];
  const int r = blockIdx.x;
  const int o = threadIdx.x;
  float v = bias[o];
#pragma unroll
  for (int s = 0; s < 32; ++s) v += part[((size_t)s * 240 + r) * ODIM + o];
  float ss = v * v;
  ss += __shfl_xor(ss, 32);
  ss += __shfl_xor(ss, 16);
  ss += __shfl_xor(ss, 8);
  ss += __shfl_xor(ss, 4);
  ss += __shfl_xor(ss, 2);
  ss += __shfl_xor(ss, 1);
  if ((o & 63) == 0) red[o >> 6] = ss;
  __syncthreads();
  float total = red[0] + red[1] + red[2] + red[3];
  out[(size_t)r * ODIM + o] = v / fmaxf(sqrtf(total), EPSF);
}

// ---------------------------------------------------------------------------
extern "C" void kernel_launch(void* const* d_in, const int* in_sizes, int n_in,
                              void* d_out, int out_size, void* d_ws, size_t ws_size,
                              hipStream_t stream) {
  const float* x       = (const float*)d_in[0];
  const float* centers = (const float*)d_in[1];
  const float* conv_w  = (const float*)d_in[2];
  const float* conv_b  = (const float*)d_in[3];
  const float* mlp_w   = (const float*)d_in[4];
  const float* mlp_b   = (const float*)d_in[5];
  float* out = (float*)d_out;

  float* ws     = (float*)d_ws;
  float* P      = ws;                       // 5,898,240 floats (23.6 MB)
  float* PA     = ws + 5898240;             // 46,080 floats
  u16*   vlad16 = (u16*)(ws + 5944320);     // 240*8192 u16 (3.9 MB)
  float* gss    = (float*)(ws + 6927360);   // 240*4 floats
  float* part   = ws;                       // [32][240][256] overlays dead P
  u16*   wbf    = (u16*)(ws + 1966080);     // 2,097,152 u16; overlays dead P after part

  k1_assign<<<dim3(8 * NCB * 2), dim3(256), 0, stream>>>(x, conv_w, conv_b, P, PA);
  k2_vlad  <<<dim3(8 * NT * 4),  dim3(256), 0, stream>>>(P, PA, centers, vlad16, gss);
  k0_wcast <<<dim3(1024),        dim3(256), 0, stream>>>(mlp_w, wbf);
  k3_gemm  <<<dim3(960),         dim3(256), 0, stream>>>(vlad16, gss, wbf, part);
  k4_out   <<<dim3(240),         dim3(256), 0, stream>>>(part, mlp_b, out);
}

// Round 2
// 227.151 us; speedup vs baseline: 1.0885x; 1.0885x over previous
//
#include <hip/hip_runtime.h>
#include <cstddef>

#define EPSF 1e-12f
#define NCB 90
#define NT 30
#define ODIM 256
#define DDIM 8192

typedef unsigned short u16;
typedef __attribute__((ext_vector_type(8))) short short8;
typedef __attribute__((ext_vector_type(4))) float float4v;

__device__ inline u16 f2bf(float f) {
  union { float f; unsigned u; } v; v.f = f;
  unsigned r = v.u + 0x7FFFu + ((v.u >> 16) & 1u);
  return (u16)(r >> 16);
}
__device__ inline float bf2f(u16 h) {
  union { unsigned u; float f; } v; v.u = ((unsigned)h) << 16;
  return v.f;
}

// ---------------------------------------------------------------------------
// K1 (MFMA): R0 dataflow (x read once, whole P rows per block) but 8 waves
// per block instead of 4. Same 720 blocks, same bytes; per-wave critical path
// halves (1 k-tile logits, 4 softmax cols, 4 P c-tiles per wave) and the
// occupancy ceiling rises 35% -> 70%. Math bit-identical to the 55us version.
// ---------------------------------------------------------------------------
__global__ __launch_bounds__(512, 6) void k1_assign(
    const float* __restrict__ x,       // [8][128][16][900]
    const float* __restrict__ conv_w,  // [64][128]
    const float* __restrict__ conv_b,  // [64]
    float* __restrict__ P,             // [8][90][64][128]
    float* __restrict__ PA)            // [8][90][64]
{
  __shared__ u16 xtf[4160];        // logits A-frags: F*520 + lane*8 + j
  __shared__ u16 xf[5120];         // P B-frags: ct*640 + (lane>>4)*160 + (lane&15)*8 + j
  __shared__ float As[64 * 33];    // logits -> exp
  __shared__ u16 afr[2048];        // a frags
  __shared__ float invs[32];       // 1/sum per column
  __shared__ float pasum[512];

  const int bx0 = blockIdx.x;      // [0,720)
  const int n = bx0 & 7;           // XCD pin
  const int cb = bx0 >> 3;
  const int t = threadIdx.x;
  const int lane = t & 63;
  const int w8 = t >> 6;           // wave 0..7

  const float* xn = x + (size_t)n * 1843200 + cb * 10;

  const int colt = w8 & 1;         // logits column tile
  const int kt = w8 >> 1;          // k-tile 0..3
  const int kr = kt * 16 + (lane & 15);
  const float bk = conv_b[kr];

  short8 wh[4], wl[4];
  {
    const int cbase = (lane >> 4) << 3;
#pragma unroll
    for (int cb32 = 0; cb32 < 4; ++cb32) {
      const float* wp = conv_w + (size_t)kr * 128 + cb32 * 32 + cbase;
      float4 u0 = *(const float4*)wp;
      float4 u1 = *(const float4*)(wp + 4);
      float fv[8] = {u0.x, u0.y, u0.z, u0.w, u1.x, u1.y, u1.z, u1.w};
      union { u16 u[8]; short8 v; } hh, ll;
#pragma unroll
      for (int j = 0; j < 8; ++j) {
        u16 h = f2bf(fv[j]);
        hh.u[j] = h;
        ll.u[j] = f2bf(fv[j] - bf2f(h));
      }
      wh[cb32] = hh.v; wl[cb32] = ll.v;
    }
  }

  float4v pacc[4];
#pragma unroll
  for (int i = 0; i < 4; ++i) pacc[i] = (float4v){0.f, 0.f, 0.f, 0.f};
  float pak = 0.f;

  // ---- prologue: load cc=0 x into registers ----
  float2 xr[4];
#pragma unroll
  for (int s = 0; s < 4; ++s) {
    int e2 = t + 512 * s;
    int c = e2 >> 4, p = e2 & 15;
    int cl = 2 * p;
    int h = cl / 10, wi = cl - 10 * h;
    xr[s] = *(const float2*)(xn + (size_t)c * 14400 + h * 900 + wi);
  }

  for (int cc = 0; cc < 5; ++cc) {
    __syncthreads();                     // prev P-mfma done before restaging
    // ---- write prefetched regs to both LDS layouts ----
#pragma unroll
    for (int s = 0; s < 4; ++s) {
      int e2 = t + 512 * s;
      int c = e2 >> 4, p = e2 & 15;
      int cl = 2 * p;
      u16 h0 = f2bf(xr[s].x), h1 = f2bf(xr[s].y);
      int ip = (c >> 4) * 640 + (p >> 2) * 160 + (c & 15) * 8 + (cl & 7);
      ushort2 pr; pr.x = h0; pr.y = h1;
      *(ushort2*)&xf[ip] = pr;
      int F = (p >> 3) * 4 + (c >> 5);
      int L = (((c >> 3) & 3) << 4) + (cl & 15);
      int i0 = F * 520 + L * 8 + (c & 7);
      xtf[i0] = h0;
      xtf[i0 + 8] = h1;
    }
    // ---- issue next cc's loads; they retire behind this cc's compute ----
    if (cc < 4) {
#pragma unroll
      for (int s = 0; s < 4; ++s) {
        int e2 = t + 512 * s;
        int c = e2 >> 4, p = e2 & 15;
        int g = (cc + 1) * 32 + 2 * p;
        int h = g / 10, wi = g - 10 * h;
        xr[s] = *(const float2*)(xn + (size_t)c * 14400 + h * 900 + wi);
      }
    }
    __syncthreads();

    // ---- logits MFMA: wave (colt, kt) computes 16 k-rows x 16 cols ----
    {
      float4v d0 = (float4v){0.f, 0.f, 0.f, 0.f};
#pragma unroll
      for (int cb32 = 0; cb32 < 4; ++cb32) {
        short8 xa = *(short8*)&xtf[(colt * 4 + cb32) * 520 + lane * 8];
        d0 = __builtin_amdgcn_mfma_f32_16x16x32_bf16(xa, wh[cb32], d0, 0, 0, 0);
        d0 = __builtin_amdgcn_mfma_f32_16x16x32_bf16(xa, wl[cb32], d0, 0, 0, 0);
      }
      int colb = colt * 16 + ((lane >> 4) << 2);
#pragma unroll
      for (int r = 0; r < 4; ++r)
        As[kr * 33 + colb + r] = d0[r] + bk;
    }
    __syncthreads();

    // ---- wave-local softmax over k for cols [4*w8, 4*w8+4) ----
    {
      const int col4 = lane & 3;
      const int kq = lane >> 2;          // 16 groups of 4 k
      const int colg = w8 * 4 + col4;
      float m = -3.4e38f;
#pragma unroll
      for (int i = 0; i < 4; ++i) m = fmaxf(m, As[(kq * 4 + i) * 33 + colg]);
      m = fmaxf(m, __shfl_xor(m, 4));
      m = fmaxf(m, __shfl_xor(m, 8));
      m = fmaxf(m, __shfl_xor(m, 16));
      m = fmaxf(m, __shfl_xor(m, 32));
      float s = 0.f;
#pragma unroll
      for (int i = 0; i < 4; ++i) {
        int a = (kq * 4 + i) * 33 + colg;
        float e = __expf(As[a] - m);
        As[a] = e;
        s += e;
      }
      s += __shfl_xor(s, 4);
      s += __shfl_xor(s, 8);
      s += __shfl_xor(s, 16);
      s += __shfl_xor(s, 32);
      if (kq == 0) invs[colg] = 1.f / s;
    }
    // ---- a-frag build (same wave's columns, no barrier needed) ----
    {
      union { u16 u[4]; ushort4 v; } cvt;
      float paks = 0.f;
#pragma unroll
      for (int j = 0; j < 4; ++j) {
        float a = As[lane * 33 + w8 * 4 + j] * invs[w8 * 4 + j];
        paks += a;
        cvt.u[j] = f2bf(a);
      }
      pak += paks;
      int dst = ((lane >> 4) * 64 + ((w8 >> 1) << 4) + (lane & 15)) * 8 + (w8 & 1) * 4;
      *(ushort4*)&afr[dst] = cvt.v;
    }
    __syncthreads();

    // ---- P MFMA: wave (kt, w8&1) owns k-tile kt, 4 of 8 c-tiles ----
    {
      short8 aa = *(short8*)&afr[((w8 >> 1) * 64 + lane) * 8];
#pragma unroll
      for (int c4 = 0; c4 < 4; ++c4) {
        int ct = (w8 & 1) * 4 + c4;
        short8 xb = *(short8*)&xf[ct * 640 + (lane >> 4) * 160 + (lane & 15) * 8];
        pacc[c4] = __builtin_amdgcn_mfma_f32_16x16x32_bf16(aa, xb, pacc[c4], 0, 0, 0);
      }
    }
  }

  float* Pp = P + (size_t)(n * NCB + cb) * DDIM;
  {
    int krow = (w8 >> 1) * 16 + ((lane >> 4) << 2);
    int c0 = (w8 & 1) * 64 + (lane & 15);
#pragma unroll
    for (int c4 = 0; c4 < 4; ++c4)
#pragma unroll
      for (int r = 0; r < 4; ++r)
        Pp[(krow + r) * 128 + c0 + c4 * 16] = pacc[c4][r];
  }
  pasum[t] = pak;
  __syncthreads();
  if (t < 64) {
    float s = 0.f;
#pragma unroll
    for (int i = 0; i < 8; ++i) s += pasum[t + 64 * i];
    PA[(size_t)(n * NCB + cb) * 64 + t] = s;
  }
}

// ---------------------------------------------------------------------------
// K2: window-outer direct sums + XCD pin; bf16 vlad out. (unchanged)
// ---------------------------------------------------------------------------
__global__ __launch_bounds__(256) void k2_vlad(
    const float* __restrict__ P, const float* __restrict__ PA,
    const float* __restrict__ centers, u16* __restrict__ vlad16,
    float* __restrict__ gss)
{
  __shared__ float Ak[16];
  __shared__ float red[4];
  const int bx0 = blockIdx.x;                    // [0,960)
  const int id = (bx0 & 7) * 120 + (bx0 >> 3);   // XCD pin: n = bx0&7
  const int n = id / 120;
  const int rem = id - n * 120;
  const int wt = rem >> 2, eb = rem & 3;
  const int win = n * NT + wt;
  const int t = threadIdx.x;

  if (t < 64) {
    int kk = t >> 2, ii = t & 3;
    float s = 0.f;
#pragma unroll
    for (int ss = 0; ss < 5; ++ss) {
      int i = ii + 4 * ss;
      int cb = (3 * wt + 80 + i) % 90;
      s += PA[((size_t)n * NCB + cb) * 64 + eb * 16 + kk];
    }
    s += __shfl_xor(s, 1);
    s += __shfl_xor(s, 2);
    if (ii == 0) Ak[kk] = s;
  }
  __syncthreads();

  const int e0 = eb * 2048 + t * 8;
  float v[8];
#pragma unroll
  for (int j = 0; j < 8; ++j) v[j] = 0.f;
#pragma unroll 5
  for (int i = 0; i < 20; ++i) {
    int cb = (3 * wt + 80 + i) % 90;
    const float* Pp = P + ((size_t)n * NCB + cb) * DDIM + e0;
    float4 u0 = *(const float4*)Pp;
    float4 u1 = *(const float4*)(Pp + 4);
    v[0] += u0.x; v[1] += u0.y; v[2] += u0.z; v[3] += u0.w;
    v[4] += u1.x; v[5] += u1.y; v[6] += u1.z; v[7] += u1.w;
  }
  const float A = Ak[t >> 4];
  const float* ce = centers + e0;
  float ss8 = 0.f;
#pragma unroll
  for (int j = 0; j < 8; ++j) {
    float val = v[j] - ce[j] * A;
    v[j] = val;
    ss8 += val * val;
  }
  float ssg = ss8;
  ssg += __shfl_xor(ssg, 1);
  ssg += __shfl_xor(ssg, 2);
  ssg += __shfl_xor(ssg, 4);
  ssg += __shfl_xor(ssg, 8);
  float rn = 1.f / fmaxf(sqrtf(ssg), EPSF);
  float ts = ss8 * rn * rn;
  ts += __shfl_xor(ts, 1);
  ts += __shfl_xor(ts, 2);
  ts += __shfl_xor(ts, 4);
  ts += __shfl_xor(ts, 8);
  ts += __shfl_xor(ts, 16);
  ts += __shfl_xor(ts, 32);
  if ((t & 63) == 0) red[t >> 6] = ts;
  __syncthreads();
  if (t == 0) gss[(size_t)win * 4 + eb] = red[0] + red[1] + red[2] + red[3];

  union { u16 u[8]; short8 s; } o;
#pragma unroll
  for (int j = 0; j < 8; ++j) o.u[j] = f2bf(v[j] * rn);
  *(short8*)(vlad16 + (size_t)win * DDIM + e0) = o.s;
}

// ---------------------------------------------------------------------------
// K0: one-time mlp_w f32 -> bf16 cast (bit-identical to k3's old per-use
// conversion; halves k3's weight bytes).
// ---------------------------------------------------------------------------
__global__ __launch_bounds__(256) void k0_wcast(
    const float* __restrict__ mlp_w, u16* __restrict__ wbf)
{
  const size_t i = (size_t)(blockIdx.x * 256 + threadIdx.x) * 8;
  float4 u0 = *(const float4*)(mlp_w + i);
  float4 u1 = *(const float4*)(mlp_w + i + 4);
  union { u16 u[8]; short8 s; } o;
  o.u[0] = f2bf(u0.x); o.u[1] = f2bf(u0.y); o.u[2] = f2bf(u0.z); o.u[3] = f2bf(u0.w);
  o.u[4] = f2bf(u1.x); o.u[5] = f2bf(u1.y); o.u[6] = f2bf(u1.z); o.u[7] = f2bf(u1.w);
  *(short8*)(wbf + i) = o.s;
}

// ---------------------------------------------------------------------------
// K3 (MFMA): bf16 weights + XCD pin on h (15 rt-blocks sharing one 64 KB
// w-slice hit the same XCD L2). part[ks][240][256] = (vlad16 @ wbf^T)*ga[r].
// ---------------------------------------------------------------------------
__global__ __launch_bounds__(256) void k3_gemm(
    const u16* __restrict__ vlad16, const float* __restrict__ gss,
    const u16* __restrict__ wbf, float* __restrict__ part)
{
  __shared__ float ga[16];
  const int bx = blockIdx.x;       // [0,960)
  const int xcd = bx & 7;
  const int i6 = bx >> 3;          // [0,120)
  const int h = xcd * 8 + (i6 & 7);  // [0,64): same h -> same XCD
  const int rt = i6 >> 3;          // [0,15)
  const int ot = h & 1;            // o half
  const int ks = h >> 1;           // 0..31, K-slice of 256
  const int t = threadIdx.x;
  const int lane = t & 63;
  const int w = t >> 6;

  if (t < 16) {
    int r = rt * 16 + t;
    float s = gss[r * 4] + gss[r * 4 + 1] + gss[r * 4 + 2] + gss[r * 4 + 3];
    ga[t] = 1.f / fmaxf(sqrtf(s), EPSF);
  }
  __syncthreads();

  const int m = lane & 15;
  const int kg = lane >> 4;
  const int d0 = ks * 256 + kg * 8;
  const u16* arow = vlad16 + (size_t)(rt * 16 + m) * DDIM + d0;

  float4v acc[2];
#pragma unroll
  for (int i = 0; i < 2; ++i) acc[i] = (float4v){0.f, 0.f, 0.f, 0.f};

#pragma unroll
  for (int ko = 0; ko < 8; ++ko) {
    short8 a = *(const short8*)(arow + ko * 32);
#pragma unroll
    for (int nt = 0; nt < 2; ++nt) {
      int o = ot * 128 + w * 32 + nt * 16 + m;
      short8 bv = *(const short8*)(wbf + (size_t)o * DDIM + d0 + ko * 32);
      acc[nt] = __builtin_amdgcn_mfma_f32_16x16x32_bf16(a, bv, acc[nt], 0, 0, 0);
    }
  }

  float g4[4];
#pragma unroll
  for (int r = 0; r < 4; ++r) g4[r] = ga[kg * 4 + r];
  float* pp = part + ((size_t)ks * 240 + rt * 16) * ODIM;
#pragma unroll
  for (int nt = 0; nt < 2; ++nt) {
    int o = ot * 128 + w * 32 + nt * 16 + m;
#pragma unroll
    for (int r = 0; r < 4; ++r)
      pp[(kg * 4 + r) * ODIM + o] = acc[nt][r] * g4[r];
  }
}

// ---------------------------------------------------------------------------
// K4: sum 32 split-K partials + bias, row-normalize 240 x 256 (unchanged)
// ---------------------------------------------------------------------------
__global__ __launch_bounds__(256) void k4_out(
    const float* __restrict__ part, const float* __restrict__ bias,
    float* __restrict__ out)
{
  __shared__ float red[4];
  const int r = blockIdx.x;
  const int o = threadIdx.x;
  float v = bias[o];
#pragma unroll
  for (int s = 0; s < 32; ++s) v += part[((size_t)s * 240 + r) * ODIM + o];
  float ss = v * v;
  ss += __shfl_xor(ss, 32);
  ss += __shfl_xor(ss, 16);
  ss += __shfl_xor(ss, 8);
  ss += __shfl_xor(ss, 4);
  ss += __shfl_xor(ss, 2);
  ss += __shfl_xor(ss, 1);
  if ((o & 63) == 0) red[o >> 6] = ss;
  __syncthreads();
  float total = red[0] + red[1] + red[2] + red[3];
  out[(size_t)r * ODIM + o] = v / fmaxf(sqrtf(total), EPSF);
}

// ---------------------------------------------------------------------------
extern "C" void kernel_launch(void* const* d_in, const int* in_sizes, int n_in,
                              void* d_out, int out_size, void* d_ws, size_t ws_size,
                              hipStream_t stream) {
  const float* x       = (const float*)d_in[0];
  const float* centers = (const float*)d_in[1];
  const float* conv_w  = (const float*)d_in[2];
  const float* conv_b  = (const float*)d_in[3];
  const float* mlp_w   = (const float*)d_in[4];
  const float* mlp_b   = (const float*)d_in[5];
  float* out = (float*)d_out;

  float* ws     = (float*)d_ws;
  float* P      = ws;                       // 5,898,240 floats (23.6 MB)
  float* PA     = ws + 5898240;             // 46,080 floats
  u16*   vlad16 = (u16*)(ws + 5944320);     // 240*8192 u16 (3.9 MB)
  float* gss    = (float*)(ws + 6927360);   // 240*4 floats
  float* part   = ws;                       // [32][240][256] overlays dead P
  u16*   wbf    = (u16*)(ws + 1966080);     // 2,097,152 u16; overlays dead P after part

  k1_assign<<<dim3(8 * NCB), dim3(512), 0, stream>>>(x, conv_w, conv_b, P, PA);
  k2_vlad  <<<dim3(8 * NT * 4), dim3(256), 0, stream>>>(P, PA, centers, vlad16, gss);
  k0_wcast <<<dim3(1024),       dim3(256), 0, stream>>>(mlp_w, wbf);
  k3_gemm  <<<dim3(960),        dim3(256), 0, stream>>>(vlad16, gss, wbf, part);
  k4_out   <<<dim3(240),        dim3(256), 0, stream>>>(part, mlp_b, out);
}

// Round 3
// 197.223 us; speedup vs baseline: 1.2537x; 1.1517x over previous
//
#include <hip/hip_runtime.h>
#include <cstddef>

#define EPSF 1e-12f
#define NCB 90
#define NT 30
#define ODIM 256
#define DDIM 8192

typedef unsigned short u16;
typedef __attribute__((ext_vector_type(8))) short short8;
typedef __attribute__((ext_vector_type(4))) float float4v;

__device__ inline u16 f2bf(float f) {
  union { float f; unsigned u; } v; v.f = f;
  unsigned r = v.u + 0x7FFFu + ((v.u >> 16) & 1u);
  return (u16)(r >> 16);
}
__device__ inline float bf2f(u16 h) {
  union { unsigned u; float f; } v; v.u = ((unsigned)h) << 16;
  return v.f;
}

// ---------------------------------------------------------------------------
// K1 (MFMA): EXACT R0 form (measured 55.5us, 83 MB). Both higher-concurrency
// variants (c-split x2, 8-wave) tripled HBM traffic to 289 MB by blowing the
// per-XCD L2 working set -- this low-concurrency form is the local optimum.
// ---------------------------------------------------------------------------
__global__ __launch_bounds__(256, 3) void k1_assign(
    const float* __restrict__ x,       // [8][128][16][900]
    const float* __restrict__ conv_w,  // [64][128]
    const float* __restrict__ conv_b,  // [64]
    float* __restrict__ P,             // [8][90][64][128]
    float* __restrict__ PA)            // [8][90][64]
{
  __shared__ u16 xtf[4160];        // logits A-frags: F*520 + lane*8 + j
  __shared__ u16 xf[5120];         // P B-frags: ct*640 + (lane>>4)*160 + (lane&15)*8 + j
  __shared__ float As[64 * 33];    // logits -> exp
  __shared__ u16 afr[2048];        // a frags
  __shared__ float invs[32];       // 1/sum per column
  __shared__ float pasum[256];

  const int bx0 = blockIdx.x;
  const int id = (bx0 & 7) * 90 + (bx0 >> 3);   // XCD pin: n = bx0&7
  const int n = id / NCB, cb = id - n * NCB;
  const int t = threadIdx.x;
  const int lane = t & 63;
  const int w = t >> 6;            // wave 0..3

  const float* xn = x + (size_t)n * 1843200 + cb * 10;

  const int colt = w & 1;
  const int kt0 = w >> 1;
  const float bk0 = conv_b[kt0 * 16 + (lane & 15)];
  const float bk1 = conv_b[(kt0 + 2) * 16 + (lane & 15)];

  short8 w0h[4], w0l[4], w1h[4], w1l[4];
  {
    int kr0 = kt0 * 16 + (lane & 15);
    int kr1 = kr0 + 32;
    int cbase = (lane >> 4) << 3;
#pragma unroll
    for (int cb32 = 0; cb32 < 4; ++cb32) {
      const float* wp0 = conv_w + (size_t)kr0 * 128 + cb32 * 32 + cbase;
      const float* wp1 = conv_w + (size_t)kr1 * 128 + cb32 * 32 + cbase;
      union { u16 u[8]; short8 v; } hh, ll;
#pragma unroll
      for (int j = 0; j < 8; ++j) {
        float fv = wp0[j];
        u16 h = f2bf(fv);
        hh.u[j] = h;
        ll.u[j] = f2bf(fv - bf2f(h));
      }
      w0h[cb32] = hh.v; w0l[cb32] = ll.v;
#pragma unroll
      for (int j = 0; j < 8; ++j) {
        float fv = wp1[j];
        u16 h = f2bf(fv);
        hh.u[j] = h;
        ll.u[j] = f2bf(fv - bf2f(h));
      }
      w1h[cb32] = hh.v; w1l[cb32] = ll.v;
    }
  }

  float4v pacc[8];
#pragma unroll
  for (int i = 0; i < 8; ++i) pacc[i] = (float4v){0.f, 0.f, 0.f, 0.f};
  float pak = 0.f;

  // ---- prologue: load cc=0 x into registers ----
  float2 xr[8];
#pragma unroll
  for (int s = 0; s < 8; ++s) {
    int e2 = t + 256 * s;
    int c = e2 >> 4, p = e2 & 15;
    int cl = 2 * p;
    int h = cl / 10, wi = cl - 10 * h;
    xr[s] = *(const float2*)(xn + (size_t)c * 14400 + h * 900 + wi);
  }

  for (int cc = 0; cc < 5; ++cc) {
    __syncthreads();                     // prev P-mfma done before restaging
    // ---- write prefetched regs to both LDS layouts ----
#pragma unroll
    for (int s = 0; s < 8; ++s) {
      int e2 = t + 256 * s;
      int c = e2 >> 4, p = e2 & 15;
      int cl = 2 * p;
      u16 h0 = f2bf(xr[s].x), h1 = f2bf(xr[s].y);
      int ip = (c >> 4) * 640 + (p >> 2) * 160 + (c & 15) * 8 + (cl & 7);
      ushort2 pr; pr.x = h0; pr.y = h1;
      *(ushort2*)&xf[ip] = pr;
      int F = (p >> 3) * 4 + (c >> 5);
      int L = (((c >> 3) & 3) << 4) + (cl & 15);
      int i0 = F * 520 + L * 8 + (c & 7);
      xtf[i0] = h0;
      xtf[i0 + 8] = h1;
    }
    // ---- issue next cc's loads; they retire behind this cc's compute ----
    if (cc < 4) {
#pragma unroll
      for (int s = 0; s < 8; ++s) {
        int e2 = t + 256 * s;
        int c = e2 >> 4, p = e2 & 15;
        int g = (cc + 1) * 32 + 2 * p;
        int h = g / 10, wi = g - 10 * h;
        xr[s] = *(const float2*)(xn + (size_t)c * 14400 + h * 900 + wi);
      }
    }
    __syncthreads();

    // ---- logits MFMA ----
    {
      float4v d0 = (float4v){0.f, 0.f, 0.f, 0.f};
      float4v d1 = (float4v){0.f, 0.f, 0.f, 0.f};
#pragma unroll
      for (int cb32 = 0; cb32 < 4; ++cb32) {
        short8 xa = *(short8*)&xtf[(colt * 4 + cb32) * 520 + lane * 8];
        d0 = __builtin_amdgcn_mfma_f32_16x16x32_bf16(xa, w0h[cb32], d0, 0, 0, 0);
        d0 = __builtin_amdgcn_mfma_f32_16x16x32_bf16(xa, w0l[cb32], d0, 0, 0, 0);
        d1 = __builtin_amdgcn_mfma_f32_16x16x32_bf16(xa, w1h[cb32], d1, 0, 0, 0);
        d1 = __builtin_amdgcn_mfma_f32_16x16x32_bf16(xa, w1l[cb32], d1, 0, 0, 0);
      }
      int colb = colt * 16 + ((lane >> 4) << 2);
      int kr0 = kt0 * 16 + (lane & 15);
      int kr1 = kr0 + 32;
#pragma unroll
      for (int r = 0; r < 4; ++r) {
        As[kr0 * 33 + colb + r] = d0[r] + bk0;
        As[kr1 * 33 + colb + r] = d1[r] + bk1;
      }
    }
    __syncthreads();

    // ---- wave-local softmax over k for cols [8w, 8w+8) ----
    {
      const int col8 = lane & 7;
      const int kq = lane >> 3;
      const int colg = w * 8 + col8;
      float m = -3.4e38f;
#pragma unroll
      for (int i = 0; i < 8; ++i) m = fmaxf(m, As[(kq * 8 + i) * 33 + colg]);
      m = fmaxf(m, __shfl_xor(m, 8));
      m = fmaxf(m, __shfl_xor(m, 16));
      m = fmaxf(m, __shfl_xor(m, 32));
      float s = 0.f;
#pragma unroll
      for (int i = 0; i < 8; ++i) {
        int a = (kq * 8 + i) * 33 + colg;
        float e = __expf(As[a] - m);
        As[a] = e;
        s += e;
      }
      s += __shfl_xor(s, 8);
      s += __shfl_xor(s, 16);
      s += __shfl_xor(s, 32);
      if (kq == 0) invs[w * 8 + col8] = 1.f / s;
    }
    // ---- a-frag build (same wave, no barrier needed) ----
    {
      union { u16 u[8]; short8 v; } cvt;
      float paks = 0.f;
#pragma unroll
      for (int j = 0; j < 8; ++j) {
        float a = As[lane * 33 + w * 8 + j] * invs[w * 8 + j];
        paks += a;
        cvt.u[j] = f2bf(a);
      }
      pak += paks;
      int dst = ((lane >> 4) * 64 + (w << 4) + (lane & 15)) * 8;
      *(short8*)&afr[dst] = cvt.v;
    }
    __syncthreads();

    // ---- P MFMA: wave w owns kt = w; 8 c-tiles ----
    {
      short8 aa = *(short8*)&afr[(w * 64 + lane) * 8];
#pragma unroll
      for (int ct = 0; ct < 8; ++ct) {
        short8 xb = *(short8*)&xf[ct * 640 + (lane >> 4) * 160 + (lane & 15) * 8];
        pacc[ct] = __builtin_amdgcn_mfma_f32_16x16x32_bf16(aa, xb, pacc[ct], 0, 0, 0);
      }
    }
  }

  float* Pp = P + (size_t)(n * NCB + cb) * DDIM;
  {
    int krow = w * 16 + ((lane >> 4) << 2);
    int c0 = lane & 15;
#pragma unroll
    for (int ct = 0; ct < 8; ++ct)
#pragma unroll
      for (int r = 0; r < 4; ++r)
        Pp[(krow + r) * 128 + ct * 16 + c0] = pacc[ct][r];
  }
  pasum[t] = pak;
  __syncthreads();
  if (t < 64)
    PA[(size_t)(n * NCB + cb) * 64 + t] =
        pasum[t] + pasum[64 + t] + pasum[128 + t] + pasum[192 + t];
}

// ---------------------------------------------------------------------------
// K2 (NEW): cumsum-over-cb windows. Windows are 20 CONSECUTIVE cb slabs
// (circular, step 3), so a register prefix scan reads P exactly ONCE
// (23.6 MB) instead of 20x (157 MB). Block = (n,k), 128 threads (thread=c).
// 61 static snapshot registers hold the needed prefixes; window sums are
// compile-time-constant prefix diffs (same trick as the JAX reference's
// cumsum, so numerics move toward the reference). gss partials [240][64]
// land in d_out (dead until k4) -- zero extra workspace.
// ---------------------------------------------------------------------------
__global__ __launch_bounds__(128) void k2_vlad(
    const float* __restrict__ P, const float* __restrict__ PA,
    const float* __restrict__ centers, u16* __restrict__ vlad16,
    float* __restrict__ gss2)          // [240][64] partials (overlays d_out)
{
  __shared__ float pa[90];
  __shared__ float aw[30];
  __shared__ float red[60];            // [wt][wave]
  const int bx = blockIdx.x;           // [0,512)
  const int n = bx & 7;                // XCD pin: same XCD that wrote P[n]
  const int k = bx >> 3;               // [0,64)
  const int t = threadIdx.x;           // c = t
  const int wid = t >> 6;

  if (t < 90) pa[t] = PA[((size_t)n * NCB + t) * 64 + k];
  __syncthreads();
  if (t < 30) {
    float s = 0.f;
#pragma unroll
    for (int i = 0; i < 20; ++i) s += pa[(3 * t + 80 + i) % 90];
    aw[t] = s;
  }

  // ---- register prefix scan over the 90 cb slabs ----
  float S0[30], S1[30], S89v;          // S0[j]=S[3j], S1[j]=S[3j+1]
  {
    float run = 0.f;
    const float* Pp = P + (size_t)n * NCB * DDIM + k * 128 + t;
#pragma unroll
    for (int cbi = 0; cbi < 90; ++cbi) {
      run += Pp[(size_t)cbi * DDIM];
      if (cbi % 3 == 0) S0[cbi / 3] = run;
      if (cbi % 3 == 1) S1[cbi / 3] = run;
      if (cbi == 89) S89v = run;
    }
  }
  const float ce = centers[k * 128 + t];
  __syncthreads();                     // aw ready

  // pass 1: per-window squared-sum partials
#pragma unroll
  for (int wt = 0; wt < 30; ++wt) {
    const int lo0 = (3 * wt + 80) % 90;
    float wsum;
    if (lo0 <= 70)
      wsum = S0[(lo0 + 19) / 3] - S1[(lo0 - 2) / 3];
    else
      wsum = S89v - S1[(lo0 - 2) / 3] + S0[(lo0 - 71) / 3];
    float v = wsum - ce * aw[wt];
    float ss = v * v;
    ss += __shfl_xor(ss, 1);
    ss += __shfl_xor(ss, 2);
    ss += __shfl_xor(ss, 4);
    ss += __shfl_xor(ss, 8);
    ss += __shfl_xor(ss, 16);
    ss += __shfl_xor(ss, 32);
    if ((t & 63) == 0) red[wt * 2 + wid] = ss;
  }
  __syncthreads();

  // pass 2: normalize + emit
#pragma unroll
  for (int wt = 0; wt < 30; ++wt) {
    const int lo0 = (3 * wt + 80) % 90;
    float wsum;
    if (lo0 <= 70)
      wsum = S0[(lo0 + 19) / 3] - S1[(lo0 - 2) / 3];
    else
      wsum = S89v - S1[(lo0 - 2) / 3] + S0[(lo0 - 71) / 3];
    float v = wsum - ce * aw[wt];
    float ss = red[wt * 2] + red[wt * 2 + 1];
    float rn = 1.f / fmaxf(sqrtf(ss), EPSF);
    vlad16[(size_t)(n * NT + wt) * DDIM + k * 128 + t] = f2bf(v * rn);
    if (t == 0) gss2[(size_t)(n * NT + wt) * 64 + k] = ss * rn * rn;
  }
}

// ---------------------------------------------------------------------------
// K0: one-time mlp_w f32 -> bf16 cast (bit-identical to k3's old per-use
// conversion; halves k3's weight bytes). Runs after k2 (wbf overlays dead P).
// ---------------------------------------------------------------------------
__global__ __launch_bounds__(256) void k0_wcast(
    const float* __restrict__ mlp_w, u16* __restrict__ wbf)
{
  const size_t i = (size_t)(blockIdx.x * 256 + threadIdx.x) * 8;
  float4 u0 = *(const float4*)(mlp_w + i);
  float4 u1 = *(const float4*)(mlp_w + i + 4);
  union { u16 u[8]; short8 s; } o;
  o.u[0] = f2bf(u0.x); o.u[1] = f2bf(u0.y); o.u[2] = f2bf(u0.z); o.u[3] = f2bf(u0.w);
  o.u[4] = f2bf(u1.x); o.u[5] = f2bf(u1.y); o.u[6] = f2bf(u1.z); o.u[7] = f2bf(u1.w);
  *(short8*)(wbf + i) = o.s;
}

// ---------------------------------------------------------------------------
// K3 (MFMA): bf16 weights + XCD pin on h. ga now sums the 64 per-k gss
// partials. part[ks][240][256] = (vlad16 @ wbf^T)*ga[r].
// ---------------------------------------------------------------------------
__global__ __launch_bounds__(256) void k3_gemm(
    const u16* __restrict__ vlad16, const float* __restrict__ gss2,
    const u16* __restrict__ wbf, float* __restrict__ part)
{
  __shared__ float ga[16];
  const int bx = blockIdx.x;       // [0,960)
  const int xcd = bx & 7;
  const int i6 = bx >> 3;          // [0,120)
  const int h = xcd * 8 + (i6 & 7);  // [0,64): same h -> same XCD
  const int rt = i6 >> 3;          // [0,15)
  const int ot = h & 1;            // o half
  const int ks = h >> 1;           // 0..31, K-slice of 256
  const int t = threadIdx.x;
  const int lane = t & 63;
  const int w = t >> 6;

  if (t < 16) {
    int r = rt * 16 + t;
    float s = 0.f;
#pragma unroll
    for (int j = 0; j < 64; ++j) s += gss2[(size_t)r * 64 + j];
    ga[t] = 1.f / fmaxf(sqrtf(s), EPSF);
  }
  __syncthreads();

  const int m = lane & 15;
  const int kg = lane >> 4;
  const int d0 = ks * 256 + kg * 8;
  const u16* arow = vlad16 + (size_t)(rt * 16 + m) * DDIM + d0;

  float4v acc[2];
#pragma unroll
  for (int i = 0; i < 2; ++i) acc[i] = (float4v){0.f, 0.f, 0.f, 0.f};

#pragma unroll
  for (int ko = 0; ko < 8; ++ko) {
    short8 a = *(const short8*)(arow + ko * 32);
#pragma unroll
    for (int nt = 0; nt < 2; ++nt) {
      int o = ot * 128 + w * 32 + nt * 16 + m;
      short8 bv = *(const short8*)(wbf + (size_t)o * DDIM + d0 + ko * 32);
      acc[nt] = __builtin_amdgcn_mfma_f32_16x16x32_bf16(a, bv, acc[nt], 0, 0, 0);
    }
  }

  float g4[4];
#pragma unroll
  for (int r = 0; r < 4; ++r) g4[r] = ga[kg * 4 + r];
  float* pp = part + ((size_t)ks * 240 + rt * 16) * ODIM;
#pragma unroll
  for (int nt = 0; nt < 2; ++nt) {
    int o = ot * 128 + w * 32 + nt * 16 + m;
#pragma unroll
    for (int r = 0; r < 4; ++r)
      pp[(kg * 4 + r) * ODIM + o] = acc[nt][r] * g4[r];
  }
}

// ---------------------------------------------------------------------------
// K4: sum 32 split-K partials + bias, row-normalize 240 x 256 (unchanged)
// ---------------------------------------------------------------------------
__global__ __launch_bounds__(256) void k4_out(
    const float* __restrict__ part, const float* __restrict__ bias,
    float* __restrict__ out)
{
  __shared__ float red[4];
  const int r = blockIdx.x;
  const int o = threadIdx.x;
  float v = bias[o];
#pragma unroll
  for (int s = 0; s < 32; ++s) v += part[((size_t)s * 240 + r) * ODIM + o];
  float ss = v * v;
  ss += __shfl_xor(ss, 32);
  ss += __shfl_xor(ss, 16);
  ss += __shfl_xor(ss, 8);
  ss += __shfl_xor(ss, 4);
  ss += __shfl_xor(ss, 2);
  ss += __shfl_xor(ss, 1);
  if ((o & 63) == 0) red[o >> 6] = ss;
  __syncthreads();
  float total = red[0] + red[1] + red[2] + red[3];
  out[(size_t)r * ODIM + o] = v / fmaxf(sqrtf(total), EPSF);
}

// ---------------------------------------------------------------------------
extern "C" void kernel_launch(void* const* d_in, const int* in_sizes, int n_in,
                              void* d_out, int out_size, void* d_ws, size_t ws_size,
                              hipStream_t stream) {
  const float* x       = (const float*)d_in[0];
  const float* centers = (const float*)d_in[1];
  const float* conv_w  = (const float*)d_in[2];
  const float* conv_b  = (const float*)d_in[3];
  const float* mlp_w   = (const float*)d_in[4];
  const float* mlp_b   = (const float*)d_in[5];
  float* out = (float*)d_out;

  float* ws     = (float*)d_ws;
  float* P      = ws;                       // 5,898,240 floats (23.6 MB)
  float* PA     = ws + 5898240;             // 46,080 floats
  u16*   vlad16 = (u16*)(ws + 5944320);     // 240*8192 u16 (3.9 MB)
  float* part   = ws;                       // [32][240][256] overlays dead P
  u16*   wbf    = (u16*)(ws + 1966080);     // 2,097,152 u16; overlays dead P
  float* gss2   = out;                      // [240][64] scratch in d_out (dead until k4)

  k1_assign<<<dim3(8 * NCB), dim3(256), 0, stream>>>(x, conv_w, conv_b, P, PA);
  k2_vlad  <<<dim3(512),     dim3(128), 0, stream>>>(P, PA, centers, vlad16, gss2);
  k0_wcast <<<dim3(1024),    dim3(256), 0, stream>>>(mlp_w, wbf);
  k3_gemm  <<<dim3(960),     dim3(256), 0, stream>>>(vlad16, gss2, wbf, part);
  k4_out   <<<dim3(240),     dim3(256), 0, stream>>>(part, mlp_b, out);
}

// Round 4
// 179.842 us; speedup vs baseline: 1.3749x; 1.0966x over previous
//
#include <hip/hip_runtime.h>
#include <cstddef>

#define EPSF 1e-12f
#define NCB 90
#define NT 30
#define ODIM 256
#define DDIM 8192

typedef unsigned short u16;
typedef __attribute__((ext_vector_type(8))) short short8;
typedef __attribute__((ext_vector_type(4))) float float4v;

__device__ inline u16 f2bf(float f) {
  union { float f; unsigned u; } v; v.f = f;
  unsigned r = v.u + 0x7FFFu + ((v.u >> 16) & 1u);
  return (u16)(r >> 16);
}
__device__ inline float bf2f(u16 h) {
  union { unsigned u; float f; } v; v.u = ((unsigned)h) << 16;
  return v.f;
}

// ---------------------------------------------------------------------------
// K1 (MFMA): EXACT R0 form (measured 55.5us, 83 MB, no spill at VGPR=84).
// Higher-concurrency variants spilled (VGPR_Count dropped, WRITE_SIZE x3).
// ---------------------------------------------------------------------------
__global__ __launch_bounds__(256, 3) void k1_assign(
    const float* __restrict__ x,       // [8][128][16][900]
    const float* __restrict__ conv_w,  // [64][128]
    const float* __restrict__ conv_b,  // [64]
    float* __restrict__ P,             // [8][90][64][128]
    float* __restrict__ PA)            // [8][90][64]
{
  __shared__ u16 xtf[4160];        // logits A-frags: F*520 + lane*8 + j
  __shared__ u16 xf[5120];         // P B-frags: ct*640 + (lane>>4)*160 + (lane&15)*8 + j
  __shared__ float As[64 * 33];    // logits -> exp
  __shared__ u16 afr[2048];        // a frags
  __shared__ float invs[32];       // 1/sum per column
  __shared__ float pasum[256];

  const int bx0 = blockIdx.x;
  const int id = (bx0 & 7) * 90 + (bx0 >> 3);   // XCD pin: n = bx0&7
  const int n = id / NCB, cb = id - n * NCB;
  const int t = threadIdx.x;
  const int lane = t & 63;
  const int w = t >> 6;            // wave 0..3

  const float* xn = x + (size_t)n * 1843200 + cb * 10;

  const int colt = w & 1;
  const int kt0 = w >> 1;
  const float bk0 = conv_b[kt0 * 16 + (lane & 15)];
  const float bk1 = conv_b[(kt0 + 2) * 16 + (lane & 15)];

  short8 w0h[4], w0l[4], w1h[4], w1l[4];
  {
    int kr0 = kt0 * 16 + (lane & 15);
    int kr1 = kr0 + 32;
    int cbase = (lane >> 4) << 3;
#pragma unroll
    for (int cb32 = 0; cb32 < 4; ++cb32) {
      const float* wp0 = conv_w + (size_t)kr0 * 128 + cb32 * 32 + cbase;
      const float* wp1 = conv_w + (size_t)kr1 * 128 + cb32 * 32 + cbase;
      union { u16 u[8]; short8 v; } hh, ll;
#pragma unroll
      for (int j = 0; j < 8; ++j) {
        float fv = wp0[j];
        u16 h = f2bf(fv);
        hh.u[j] = h;
        ll.u[j] = f2bf(fv - bf2f(h));
      }
      w0h[cb32] = hh.v; w0l[cb32] = ll.v;
#pragma unroll
      for (int j = 0; j < 8; ++j) {
        float fv = wp1[j];
        u16 h = f2bf(fv);
        hh.u[j] = h;
        ll.u[j] = f2bf(fv - bf2f(h));
      }
      w1h[cb32] = hh.v; w1l[cb32] = ll.v;
    }
  }

  float4v pacc[8];
#pragma unroll
  for (int i = 0; i < 8; ++i) pacc[i] = (float4v){0.f, 0.f, 0.f, 0.f};
  float pak = 0.f;

  // ---- prologue: load cc=0 x into registers ----
  float2 xr[8];
#pragma unroll
  for (int s = 0; s < 8; ++s) {
    int e2 = t + 256 * s;
    int c = e2 >> 4, p = e2 & 15;
    int cl = 2 * p;
    int h = cl / 10, wi = cl - 10 * h;
    xr[s] = *(const float2*)(xn + (size_t)c * 14400 + h * 900 + wi);
  }

  for (int cc = 0; cc < 5; ++cc) {
    __syncthreads();                     // prev P-mfma done before restaging
    // ---- write prefetched regs to both LDS layouts ----
#pragma unroll
    for (int s = 0; s < 8; ++s) {
      int e2 = t + 256 * s;
      int c = e2 >> 4, p = e2 & 15;
      int cl = 2 * p;
      u16 h0 = f2bf(xr[s].x), h1 = f2bf(xr[s].y);
      int ip = (c >> 4) * 640 + (p >> 2) * 160 + (c & 15) * 8 + (cl & 7);
      ushort2 pr; pr.x = h0; pr.y = h1;
      *(ushort2*)&xf[ip] = pr;
      int F = (p >> 3) * 4 + (c >> 5);
      int L = (((c >> 3) & 3) << 4) + (cl & 15);
      int i0 = F * 520 + L * 8 + (c & 7);
      xtf[i0] = h0;
      xtf[i0 + 8] = h1;
    }
    // ---- issue next cc's loads; they retire behind this cc's compute ----
    if (cc < 4) {
#pragma unroll
      for (int s = 0; s < 8; ++s) {
        int e2 = t + 256 * s;
        int c = e2 >> 4, p = e2 & 15;
        int g = (cc + 1) * 32 + 2 * p;
        int h = g / 10, wi = g - 10 * h;
        xr[s] = *(const float2*)(xn + (size_t)c * 14400 + h * 900 + wi);
      }
    }
    __syncthreads();

    // ---- logits MFMA ----
    {
      float4v d0 = (float4v){0.f, 0.f, 0.f, 0.f};
      float4v d1 = (float4v){0.f, 0.f, 0.f, 0.f};
#pragma unroll
      for (int cb32 = 0; cb32 < 4; ++cb32) {
        short8 xa = *(short8*)&xtf[(colt * 4 + cb32) * 520 + lane * 8];
        d0 = __builtin_amdgcn_mfma_f32_16x16x32_bf16(xa, w0h[cb32], d0, 0, 0, 0);
        d0 = __builtin_amdgcn_mfma_f32_16x16x32_bf16(xa, w0l[cb32], d0, 0, 0, 0);
        d1 = __builtin_amdgcn_mfma_f32_16x16x32_bf16(xa, w1h[cb32], d1, 0, 0, 0);
        d1 = __builtin_amdgcn_mfma_f32_16x16x32_bf16(xa, w1l[cb32], d1, 0, 0, 0);
      }
      int colb = colt * 16 + ((lane >> 4) << 2);
      int kr0 = kt0 * 16 + (lane & 15);
      int kr1 = kr0 + 32;
#pragma unroll
      for (int r = 0; r < 4; ++r) {
        As[kr0 * 33 + colb + r] = d0[r] + bk0;
        As[kr1 * 33 + colb + r] = d1[r] + bk1;
      }
    }
    __syncthreads();

    // ---- wave-local softmax over k for cols [8w, 8w+8) ----
    {
      const int col8 = lane & 7;
      const int kq = lane >> 3;
      const int colg = w * 8 + col8;
      float m = -3.4e38f;
#pragma unroll
      for (int i = 0; i < 8; ++i) m = fmaxf(m, As[(kq * 8 + i) * 33 + colg]);
      m = fmaxf(m, __shfl_xor(m, 8));
      m = fmaxf(m, __shfl_xor(m, 16));
      m = fmaxf(m, __shfl_xor(m, 32));
      float s = 0.f;
#pragma unroll
      for (int i = 0; i < 8; ++i) {
        int a = (kq * 8 + i) * 33 + colg;
        float e = __expf(As[a] - m);
        As[a] = e;
        s += e;
      }
      s += __shfl_xor(s, 8);
      s += __shfl_xor(s, 16);
      s += __shfl_xor(s, 32);
      if (kq == 0) invs[w * 8 + col8] = 1.f / s;
    }
    // ---- a-frag build (same wave, no barrier needed) ----
    {
      union { u16 u[8]; short8 v; } cvt;
      float paks = 0.f;
#pragma unroll
      for (int j = 0; j < 8; ++j) {
        float a = As[lane * 33 + w * 8 + j] * invs[w * 8 + j];
        paks += a;
        cvt.u[j] = f2bf(a);
      }
      pak += paks;
      int dst = ((lane >> 4) * 64 + (w << 4) + (lane & 15)) * 8;
      *(short8*)&afr[dst] = cvt.v;
    }
    __syncthreads();

    // ---- P MFMA: wave w owns kt = w; 8 c-tiles ----
    {
      short8 aa = *(short8*)&afr[(w * 64 + lane) * 8];
#pragma unroll
      for (int ct = 0; ct < 8; ++ct) {
        short8 xb = *(short8*)&xf[ct * 640 + (lane >> 4) * 160 + (lane & 15) * 8];
        pacc[ct] = __builtin_amdgcn_mfma_f32_16x16x32_bf16(aa, xb, pacc[ct], 0, 0, 0);
      }
    }
  }

  float* Pp = P + (size_t)(n * NCB + cb) * DDIM;
  {
    int krow = w * 16 + ((lane >> 4) << 2);
    int c0 = lane & 15;
#pragma unroll
    for (int ct = 0; ct < 8; ++ct)
#pragma unroll
      for (int r = 0; r < 4; ++r)
        Pp[(krow + r) * 128 + ct * 16 + c0] = pacc[ct][r];
  }
  pasum[t] = pak;
  __syncthreads();
  if (t < 64)
    PA[(size_t)(n * NCB + cb) * 64 + t] =
        pasum[t] + pasum[64 + t] + pasum[128 + t] + pasum[192 + t];
}

// ---------------------------------------------------------------------------
// K2a (NEW): disjoint 3-slab group sums G[n][j] = P[3j]+P[3j+1]+P[3j+2],
// written IN PLACE over P[n][3j+1] (k2b only needs slabs with cb%3 in {0,2}).
// Element-wise, same thread reads then writes its own element -> no hazard.
// Fully parallel, tiny register footprint (no spill risk).
// ---------------------------------------------------------------------------
__global__ __launch_bounds__(256) void k2a_group(float* __restrict__ P)
{
  const int bx0 = blockIdx.x;        // [0,480)
  const int n = bx0 & 7;             // XCD pin
  const int rest = bx0 >> 3;         // [0,60)
  const int j = rest >> 1;
  const int seg = rest & 1;
  const int t = threadIdx.x;

  float* s0 = P + ((size_t)n * NCB + 3 * j) * DDIM + seg * 4096;
  float* s1 = s0 + DDIM;
  float* s2 = s1 + DDIM;
#pragma unroll
  for (int i = 0; i < 4; ++i) {
    int e = t * 4 + i * 1024;
    float4 a = *(const float4*)(s0 + e);
    float4 b = *(const float4*)(s1 + e);
    float4 c = *(const float4*)(s2 + e);
    float4 o;
    o.x = a.x + b.x + c.x; o.y = a.y + b.y + c.y;
    o.z = a.z + b.z + c.z; o.w = a.w + b.w + c.w;
    *(float4*)(s1 + e) = o;
  }
}

// ---------------------------------------------------------------------------
// K2b: R0's verified k2 structure, but window = P[a] + 6 group slabs + P[b]
// (8 slab-adds instead of 20). a = (3wt+80)%90 (cb%3==2), interior = groups
// wt+27..wt+32 (stored at slab 3g+1), b = (3wt+99)%90 (cb%3==0).
// ---------------------------------------------------------------------------
__global__ __launch_bounds__(256) void k2_vlad(
    const float* __restrict__ P, const float* __restrict__ PA,
    const float* __restrict__ centers, u16* __restrict__ vlad16,
    float* __restrict__ gss)
{
  __shared__ float Ak[16];
  __shared__ float red[4];
  const int bx0 = blockIdx.x;                    // [0,960)
  const int id = (bx0 & 7) * 120 + (bx0 >> 3);   // XCD pin: n = bx0&7
  const int n = id / 120;
  const int rem = id - n * 120;
  const int wt = rem >> 2, eb = rem & 3;
  const int win = n * NT + wt;
  const int t = threadIdx.x;

  if (t < 64) {
    int kk = t >> 2, ii = t & 3;
    float s = 0.f;
#pragma unroll
    for (int ss = 0; ss < 5; ++ss) {
      int i = ii + 4 * ss;
      int cb = (3 * wt + 80 + i) % 90;
      s += PA[((size_t)n * NCB + cb) * 64 + eb * 16 + kk];
    }
    s += __shfl_xor(s, 1);
    s += __shfl_xor(s, 2);
    if (ii == 0) Ak[kk] = s;
  }
  __syncthreads();

  const int e0 = eb * 2048 + t * 8;
  const float* base = P + (size_t)n * NCB * DDIM + e0;
  float v[8];
#pragma unroll
  for (int j = 0; j < 8; ++j) v[j] = 0.f;

  // slab list: 2 edges + 6 groups
  int slab[8];
  slab[0] = (3 * wt + 80) % 90;                   // edge, cb%3==2
  slab[7] = (3 * wt + 99) % 90;                   // edge, cb%3==0
#pragma unroll
  for (int g = 0; g < 6; ++g) slab[1 + g] = 3 * ((wt + 27 + g) % 30) + 1;  // G slabs

#pragma unroll
  for (int i = 0; i < 8; ++i) {
    const float* Pp = base + (size_t)slab[i] * DDIM;
    float4 u0 = *(const float4*)Pp;
    float4 u1 = *(const float4*)(Pp + 4);
    v[0] += u0.x; v[1] += u0.y; v[2] += u0.z; v[3] += u0.w;
    v[4] += u1.x; v[5] += u1.y; v[6] += u1.z; v[7] += u1.w;
  }

  const float A = Ak[t >> 4];
  const float* ce = centers + e0;
  float ss8 = 0.f;
#pragma unroll
  for (int j = 0; j < 8; ++j) {
    float val = v[j] - ce[j] * A;
    v[j] = val;
    ss8 += val * val;
  }
  float ssg = ss8;
  ssg += __shfl_xor(ssg, 1);
  ssg += __shfl_xor(ssg, 2);
  ssg += __shfl_xor(ssg, 4);
  ssg += __shfl_xor(ssg, 8);
  float rn = 1.f / fmaxf(sqrtf(ssg), EPSF);
  float ts = ss8 * rn * rn;
  ts += __shfl_xor(ts, 1);
  ts += __shfl_xor(ts, 2);
  ts += __shfl_xor(ts, 4);
  ts += __shfl_xor(ts, 8);
  ts += __shfl_xor(ts, 16);
  ts += __shfl_xor(ts, 32);
  if ((t & 63) == 0) red[t >> 6] = ts;
  __syncthreads();
  if (t == 0) gss[(size_t)win * 4 + eb] = red[0] + red[1] + red[2] + red[3];

  union { u16 u[8]; short8 s; } o;
#pragma unroll
  for (int j = 0; j < 8; ++j) o.u[j] = f2bf(v[j] * rn);
  *(short8*)(vlad16 + (size_t)win * DDIM + e0) = o.s;
}

// ---------------------------------------------------------------------------
// K0: one-time mlp_w f32 -> bf16 cast (bit-identical to per-use conversion).
// ---------------------------------------------------------------------------
__global__ __launch_bounds__(256) void k0_wcast(
    const float* __restrict__ mlp_w, u16* __restrict__ wbf)
{
  const size_t i = (size_t)(blockIdx.x * 256 + threadIdx.x) * 8;
  float4 u0 = *(const float4*)(mlp_w + i);
  float4 u1 = *(const float4*)(mlp_w + i + 4);
  union { u16 u[8]; short8 s; } o;
  o.u[0] = f2bf(u0.x); o.u[1] = f2bf(u0.y); o.u[2] = f2bf(u0.z); o.u[3] = f2bf(u0.w);
  o.u[4] = f2bf(u1.x); o.u[5] = f2bf(u1.y); o.u[6] = f2bf(u1.z); o.u[7] = f2bf(u1.w);
  *(short8*)(wbf + i) = o.s;
}

// ---------------------------------------------------------------------------
// K3 (MFMA): bf16 weights + XCD pin on h. ga = R0 form (4 gss partials).
// part[ks][240][256] = (vlad16 @ wbf^T)*ga[r].
// ---------------------------------------------------------------------------
__global__ __launch_bounds__(256) void k3_gemm(
    const u16* __restrict__ vlad16, const float* __restrict__ gss,
    const u16* __restrict__ wbf, float* __restrict__ part)
{
  __shared__ float ga[16];
  const int bx = blockIdx.x;       // [0,960)
  const int xcd = bx & 7;
  const int i6 = bx >> 3;          // [0,120)
  const int h = xcd * 8 + (i6 & 7);  // [0,64): same h -> same XCD
  const int rt = i6 >> 3;          // [0,15)
  const int ot = h & 1;            // o half
  const int ks = h >> 1;           // 0..31, K-slice of 256
  const int t = threadIdx.x;
  const int lane = t & 63;
  const int w = t >> 6;

  if (t < 16) {
    int r = rt * 16 + t;
    float s = gss[r * 4] + gss[r * 4 + 1] + gss[r * 4 + 2] + gss[r * 4 + 3];
    ga[t] = 1.f / fmaxf(sqrtf(s), EPSF);
  }
  __syncthreads();

  const int m = lane & 15;
  const int kg = lane >> 4;
  const int d0 = ks * 256 + kg * 8;
  const u16* arow = vlad16 + (size_t)(rt * 16 + m) * DDIM + d0;

  float4v acc[2];
#pragma unroll
  for (int i = 0; i < 2; ++i) acc[i] = (float4v){0.f, 0.f, 0.f, 0.f};

#pragma unroll
  for (int ko = 0; ko < 8; ++ko) {
    short8 a = *(const short8*)(arow + ko * 32);
#pragma unroll
    for (int nt = 0; nt < 2; ++nt) {
      int o = ot * 128 + w * 32 + nt * 16 + m;
      short8 bv = *(const short8*)(wbf + (size_t)o * DDIM + d0 + ko * 32);
      acc[nt] = __builtin_amdgcn_mfma_f32_16x16x32_bf16(a, bv, acc[nt], 0, 0, 0);
    }
  }

  float g4[4];
#pragma unroll
  for (int r = 0; r < 4; ++r) g4[r] = ga[kg * 4 + r];
  float* pp = part + ((size_t)ks * 240 + rt * 16) * ODIM;
#pragma unroll
  for (int nt = 0; nt < 2; ++nt) {
    int o = ot * 128 + w * 32 + nt * 16 + m;
#pragma unroll
    for (int r = 0; r < 4; ++r)
      pp[(kg * 4 + r) * ODIM + o] = acc[nt][r] * g4[r];
  }
}

// ---------------------------------------------------------------------------
// K4: sum 32 split-K partials + bias, row-normalize 240 x 256 (unchanged)
// ---------------------------------------------------------------------------
__global__ __launch_bounds__(256) void k4_out(
    const float* __restrict__ part, const float* __restrict__ bias,
    float* __restrict__ out)
{
  __shared__ float red[4];
  const int r = blockIdx.x;
  const int o = threadIdx.x;
  float v = bias[o];
#pragma unroll
  for (int s = 0; s < 32; ++s) v += part[((size_t)s * 240 + r) * ODIM + o];
  float ss = v * v;
  ss += __shfl_xor(ss, 32);
  ss += __shfl_xor(ss, 16);
  ss += __shfl_xor(ss, 8);
  ss += __shfl_xor(ss, 4);
  ss += __shfl_xor(ss, 2);
  ss += __shfl_xor(ss, 1);
  if ((o & 63) == 0) red[o >> 6] = ss;
  __syncthreads();
  float total = red[0] + red[1] + red[2] + red[3];
  out[(size_t)r * ODIM + o] = v / fmaxf(sqrtf(total), EPSF);
}

// ---------------------------------------------------------------------------
extern "C" void kernel_launch(void* const* d_in, const int* in_sizes, int n_in,
                              void* d_out, int out_size, void* d_ws, size_t ws_size,
                              hipStream_t stream) {
  const float* x       = (const float*)d_in[0];
  const float* centers = (const float*)d_in[1];
  const float* conv_w  = (const float*)d_in[2];
  const float* conv_b  = (const float*)d_in[3];
  const float* mlp_w   = (const float*)d_in[4];
  const float* mlp_b   = (const float*)d_in[5];
  float* out = (float*)d_out;

  float* ws     = (float*)d_ws;
  float* P      = ws;                       // 5,898,240 floats (23.6 MB)
  float* PA     = ws + 5898240;             // 46,080 floats
  u16*   vlad16 = (u16*)(ws + 5944320);     // 240*8192 u16 (3.9 MB)
  float* gss    = (float*)(ws + 6927360);   // 240*4 floats
  float* part   = ws;                       // [32][240][256] overlays dead P
  u16*   wbf    = (u16*)(ws + 1966080);     // 2,097,152 u16; overlays dead P

  k1_assign<<<dim3(8 * NCB), dim3(256), 0, stream>>>(x, conv_w, conv_b, P, PA);
  k2a_group<<<dim3(480),     dim3(256), 0, stream>>>(P);
  k2_vlad  <<<dim3(8 * NT * 4), dim3(256), 0, stream>>>(P, PA, centers, vlad16, gss);
  k0_wcast <<<dim3(1024),    dim3(256), 0, stream>>>(mlp_w, wbf);
  k3_gemm  <<<dim3(960),     dim3(256), 0, stream>>>(vlad16, gss, wbf, part);
  k4_out   <<<dim3(240),     dim3(256), 0, stream>>>(part, mlp_b, out);
}

// Round 5
// 172.399 us; speedup vs baseline: 1.4342x; 1.0432x over previous
//
#include <hip/hip_runtime.h>
#include <cstddef>

#define EPSF 1e-12f
#define NCB 90
#define NT 30
#define ODIM 256
#define DDIM 8192

typedef unsigned short u16;
typedef __attribute__((ext_vector_type(8))) short short8;
typedef __attribute__((ext_vector_type(4))) float float4v;

__device__ inline u16 f2bf(float f) {
  union { float f; unsigned u; } v; v.f = f;
  unsigned r = v.u + 0x7FFFu + ((v.u >> 16) & 1u);
  return (u16)(r >> 16);
}
__device__ inline float bf2f(u16 h) {
  union { unsigned u; float f; } v; v.u = ((unsigned)h) << 16;
  return v.f;
}

// ---------------------------------------------------------------------------
// K1 (MFMA): EXACT R0 form (measured 55.5us, 83 MB, no spill at VGPR=84).
// Every higher-concurrency variant spilled or blew the per-XCD L2 working
// set (traffic x3.5). Do not touch.
// ---------------------------------------------------------------------------
__global__ __launch_bounds__(256, 3) void k1_assign(
    const float* __restrict__ x,       // [8][128][16][900]
    const float* __restrict__ conv_w,  // [64][128]
    const float* __restrict__ conv_b,  // [64]
    float* __restrict__ P,             // [8][90][64][128]
    float* __restrict__ PA)            // [8][90][64]
{
  __shared__ u16 xtf[4160];        // logits A-frags: F*520 + lane*8 + j
  __shared__ u16 xf[5120];         // P B-frags: ct*640 + (lane>>4)*160 + (lane&15)*8 + j
  __shared__ float As[64 * 33];    // logits -> exp
  __shared__ u16 afr[2048];        // a frags
  __shared__ float invs[32];       // 1/sum per column
  __shared__ float pasum[256];

  const int bx0 = blockIdx.x;
  const int id = (bx0 & 7) * 90 + (bx0 >> 3);   // XCD pin: n = bx0&7
  const int n = id / NCB, cb = id - n * NCB;
  const int t = threadIdx.x;
  const int lane = t & 63;
  const int w = t >> 6;            // wave 0..3

  const float* xn = x + (size_t)n * 1843200 + cb * 10;

  const int colt = w & 1;
  const int kt0 = w >> 1;
  const float bk0 = conv_b[kt0 * 16 + (lane & 15)];
  const float bk1 = conv_b[(kt0 + 2) * 16 + (lane & 15)];

  short8 w0h[4], w0l[4], w1h[4], w1l[4];
  {
    int kr0 = kt0 * 16 + (lane & 15);
    int kr1 = kr0 + 32;
    int cbase = (lane >> 4) << 3;
#pragma unroll
    for (int cb32 = 0; cb32 < 4; ++cb32) {
      const float* wp0 = conv_w + (size_t)kr0 * 128 + cb32 * 32 + cbase;
      const float* wp1 = conv_w + (size_t)kr1 * 128 + cb32 * 32 + cbase;
      union { u16 u[8]; short8 v; } hh, ll;
#pragma unroll
      for (int j = 0; j < 8; ++j) {
        float fv = wp0[j];
        u16 h = f2bf(fv);
        hh.u[j] = h;
        ll.u[j] = f2bf(fv - bf2f(h));
      }
      w0h[cb32] = hh.v; w0l[cb32] = ll.v;
#pragma unroll
      for (int j = 0; j < 8; ++j) {
        float fv = wp1[j];
        u16 h = f2bf(fv);
        hh.u[j] = h;
        ll.u[j] = f2bf(fv - bf2f(h));
      }
      w1h[cb32] = hh.v; w1l[cb32] = ll.v;
    }
  }

  float4v pacc[8];
#pragma unroll
  for (int i = 0; i < 8; ++i) pacc[i] = (float4v){0.f, 0.f, 0.f, 0.f};
  float pak = 0.f;

  // ---- prologue: load cc=0 x into registers ----
  float2 xr[8];
#pragma unroll
  for (int s = 0; s < 8; ++s) {
    int e2 = t + 256 * s;
    int c = e2 >> 4, p = e2 & 15;
    int cl = 2 * p;
    int h = cl / 10, wi = cl - 10 * h;
    xr[s] = *(const float2*)(xn + (size_t)c * 14400 + h * 900 + wi);
  }

  for (int cc = 0; cc < 5; ++cc) {
    __syncthreads();                     // prev P-mfma done before restaging
    // ---- write prefetched regs to both LDS layouts ----
#pragma unroll
    for (int s = 0; s < 8; ++s) {
      int e2 = t + 256 * s;
      int c = e2 >> 4, p = e2 & 15;
      int cl = 2 * p;
      u16 h0 = f2bf(xr[s].x), h1 = f2bf(xr[s].y);
      int ip = (c >> 4) * 640 + (p >> 2) * 160 + (c & 15) * 8 + (cl & 7);
      ushort2 pr; pr.x = h0; pr.y = h1;
      *(ushort2*)&xf[ip] = pr;
      int F = (p >> 3) * 4 + (c >> 5);
      int L = (((c >> 3) & 3) << 4) + (cl & 15);
      int i0 = F * 520 + L * 8 + (c & 7);
      xtf[i0] = h0;
      xtf[i0 + 8] = h1;
    }
    // ---- issue next cc's loads; they retire behind this cc's compute ----
    if (cc < 4) {
#pragma unroll
      for (int s = 0; s < 8; ++s) {
        int e2 = t + 256 * s;
        int c = e2 >> 4, p = e2 & 15;
        int g = (cc + 1) * 32 + 2 * p;
        int h = g / 10, wi = g - 10 * h;
        xr[s] = *(const float2*)(xn + (size_t)c * 14400 + h * 900 + wi);
      }
    }
    __syncthreads();

    // ---- logits MFMA ----
    {
      float4v d0 = (float4v){0.f, 0.f, 0.f, 0.f};
      float4v d1 = (float4v){0.f, 0.f, 0.f, 0.f};
#pragma unroll
      for (int cb32 = 0; cb32 < 4; ++cb32) {
        short8 xa = *(short8*)&xtf[(colt * 4 + cb32) * 520 + lane * 8];
        d0 = __builtin_amdgcn_mfma_f32_16x16x32_bf16(xa, w0h[cb32], d0, 0, 0, 0);
        d0 = __builtin_amdgcn_mfma_f32_16x16x32_bf16(xa, w0l[cb32], d0, 0, 0, 0);
        d1 = __builtin_amdgcn_mfma_f32_16x16x32_bf16(xa, w1h[cb32], d1, 0, 0, 0);
        d1 = __builtin_amdgcn_mfma_f32_16x16x32_bf16(xa, w1l[cb32], d1, 0, 0, 0);
      }
      int colb = colt * 16 + ((lane >> 4) << 2);
      int kr0 = kt0 * 16 + (lane & 15);
      int kr1 = kr0 + 32;
#pragma unroll
      for (int r = 0; r < 4; ++r) {
        As[kr0 * 33 + colb + r] = d0[r] + bk0;
        As[kr1 * 33 + colb + r] = d1[r] + bk1;
      }
    }
    __syncthreads();

    // ---- wave-local softmax over k for cols [8w, 8w+8) ----
    {
      const int col8 = lane & 7;
      const int kq = lane >> 3;
      const int colg = w * 8 + col8;
      float m = -3.4e38f;
#pragma unroll
      for (int i = 0; i < 8; ++i) m = fmaxf(m, As[(kq * 8 + i) * 33 + colg]);
      m = fmaxf(m, __shfl_xor(m, 8));
      m = fmaxf(m, __shfl_xor(m, 16));
      m = fmaxf(m, __shfl_xor(m, 32));
      float s = 0.f;
#pragma unroll
      for (int i = 0; i < 8; ++i) {
        int a = (kq * 8 + i) * 33 + colg;
        float e = __expf(As[a] - m);
        As[a] = e;
        s += e;
      }
      s += __shfl_xor(s, 8);
      s += __shfl_xor(s, 16);
      s += __shfl_xor(s, 32);
      if (kq == 0) invs[w * 8 + col8] = 1.f / s;
    }
    // ---- a-frag build (same wave, no barrier needed) ----
    {
      union { u16 u[8]; short8 v; } cvt;
      float paks = 0.f;
#pragma unroll
      for (int j = 0; j < 8; ++j) {
        float a = As[lane * 33 + w * 8 + j] * invs[w * 8 + j];
        paks += a;
        cvt.u[j] = f2bf(a);
      }
      pak += paks;
      int dst = ((lane >> 4) * 64 + (w << 4) + (lane & 15)) * 8;
      *(short8*)&afr[dst] = cvt.v;
    }
    __syncthreads();

    // ---- P MFMA: wave w owns kt = w; 8 c-tiles ----
    {
      short8 aa = *(short8*)&afr[(w * 64 + lane) * 8];
#pragma unroll
      for (int ct = 0; ct < 8; ++ct) {
        short8 xb = *(short8*)&xf[ct * 640 + (lane >> 4) * 160 + (lane & 15) * 8];
        pacc[ct] = __builtin_amdgcn_mfma_f32_16x16x32_bf16(aa, xb, pacc[ct], 0, 0, 0);
      }
    }
  }

  float* Pp = P + (size_t)(n * NCB + cb) * DDIM;
  {
    int krow = w * 16 + ((lane >> 4) << 2);
    int c0 = lane & 15;
#pragma unroll
    for (int ct = 0; ct < 8; ++ct)
#pragma unroll
      for (int r = 0; r < 4; ++r)
        Pp[(krow + r) * 128 + ct * 16 + c0] = pacc[ct][r];
  }
  pasum[t] = pak;
  __syncthreads();
  if (t < 64)
    PA[(size_t)(n * NCB + cb) * 64 + t] =
        pasum[t] + pasum[64 + t] + pasum[128 + t] + pasum[192 + t];
}

// ---------------------------------------------------------------------------
// K2: R0's verified 20-read form, but eb split 8 -> 1920 blocks (7.5/CU) for
// latency hiding. Same traffic, same per-element add order (bitwise-identical
// v). Per-thread: 20 independent float4 loads. gss widens to [240][8].
// ---------------------------------------------------------------------------
__global__ __launch_bounds__(256) void k2_vlad(
    const float* __restrict__ P, const float* __restrict__ PA,
    const float* __restrict__ centers, u16* __restrict__ vlad16,
    float* __restrict__ gss)            // [240][8]
{
  __shared__ float Ak[8];
  __shared__ float red[4];
  const int bx0 = blockIdx.x;                    // [0,1920)
  const int id = (bx0 & 7) * 240 + (bx0 >> 3);   // XCD pin: n = bx0&7
  const int n = id / 240;
  const int rem = id - n * 240;
  const int wt = rem >> 3, eb = rem & 7;
  const int win = n * NT + wt;
  const int t = threadIdx.x;

  if (t < 32) {
    int kk = t >> 2, ii = t & 3;
    float s = 0.f;
#pragma unroll
    for (int ss = 0; ss < 5; ++ss) {
      int i = ii + 4 * ss;
      int cb = (3 * wt + 80 + i) % 90;
      s += PA[((size_t)n * NCB + cb) * 64 + eb * 8 + kk];
    }
    s += __shfl_xor(s, 1);
    s += __shfl_xor(s, 2);
    if (ii == 0) Ak[kk] = s;
  }
  __syncthreads();

  const int e0 = eb * 1024 + t * 4;     // global (k,c) offset in [0,8192)
  const float* base = P + (size_t)n * NCB * DDIM + e0;
  float v[4];
#pragma unroll
  for (int j = 0; j < 4; ++j) v[j] = 0.f;
#pragma unroll 5
  for (int i = 0; i < 20; ++i) {
    int cb = (3 * wt + 80 + i) % 90;
    float4 u0 = *(const float4*)(base + (size_t)cb * DDIM);
    v[0] += u0.x; v[1] += u0.y; v[2] += u0.z; v[3] += u0.w;
  }

  const float A = Ak[t >> 5];           // k_local = t/32
  const float* ce = centers + e0;
  float ss8 = 0.f;
#pragma unroll
  for (int j = 0; j < 4; ++j) {
    float val = v[j] - ce[j] * A;
    v[j] = val;
    ss8 += val * val;
  }
  // per-k (32-thread group) reduction for intra-norm
  float ssg = ss8;
  ssg += __shfl_xor(ssg, 1);
  ssg += __shfl_xor(ssg, 2);
  ssg += __shfl_xor(ssg, 4);
  ssg += __shfl_xor(ssg, 8);
  ssg += __shfl_xor(ssg, 16);
  float rn = 1.f / fmaxf(sqrtf(ssg), EPSF);
  // block-wide sum of normalized squares (for global norm)
  float ts = ss8 * rn * rn;
  ts += __shfl_xor(ts, 1);
  ts += __shfl_xor(ts, 2);
  ts += __shfl_xor(ts, 4);
  ts += __shfl_xor(ts, 8);
  ts += __shfl_xor(ts, 16);
  ts += __shfl_xor(ts, 32);
  if ((t & 63) == 0) red[t >> 6] = ts;
  __syncthreads();
  if (t == 0) gss[(size_t)win * 8 + eb] = red[0] + red[1] + red[2] + red[3];

  union { u16 u[4]; ushort4 v4; } o;
#pragma unroll
  for (int j = 0; j < 4; ++j) o.u[j] = f2bf(v[j] * rn);
  *(ushort4*)(vlad16 + (size_t)win * DDIM + e0) = o.v4;
}

// ---------------------------------------------------------------------------
// K3 (MFMA): exact R0 form (f32 mlp_w, per-use f2bf -- measured neutral vs
// bf16 precast, and saves the k0 launch). ga sums 8 gss partials now.
// part[ks][240][256] = (vlad16 @ bf16(mlp_w)^T) * ga[r].
// ---------------------------------------------------------------------------
__global__ __launch_bounds__(256) void k3_gemm(
    const u16* __restrict__ vlad16, const float* __restrict__ gss,
    const float* __restrict__ mlp_w, float* __restrict__ part)
{
  __shared__ float ga[16];
  const int bx = blockIdx.x;
  const int rt = bx % 15;
  const int h = bx / 15;           // [0,64)
  const int ot = h & 1;            // o half
  const int ks = h >> 1;           // 0..31, K-slice of 256
  const int t = threadIdx.x;
  const int lane = t & 63;
  const int w = t >> 6;

  if (t < 16) {
    int r = rt * 16 + t;
    float s = 0.f;
#pragma unroll
    for (int j = 0; j < 8; ++j) s += gss[(size_t)r * 8 + j];
    ga[t] = 1.f / fmaxf(sqrtf(s), EPSF);
  }
  __syncthreads();

  const int m = lane & 15;
  const int kg = lane >> 4;
  const int d0 = ks * 256 + kg * 8;
  const u16* arow = vlad16 + (size_t)(rt * 16 + m) * DDIM + d0;

  float4v acc[2];
#pragma unroll
  for (int i = 0; i < 2; ++i) acc[i] = (float4v){0.f, 0.f, 0.f, 0.f};

#pragma unroll
  for (int ko = 0; ko < 8; ++ko) {
    short8 a = *(const short8*)(arow + ko * 32);
#pragma unroll
    for (int nt = 0; nt < 2; ++nt) {
      int o = ot * 128 + w * 32 + nt * 16 + m;
      const float* wrow = mlp_w + (size_t)o * DDIM + d0 + ko * 32;
      float4 u0 = *(const float4*)wrow;
      float4 u1 = *(const float4*)(wrow + 4);
      union { u16 u[8]; short8 v; } bb;
      bb.u[0] = f2bf(u0.x); bb.u[1] = f2bf(u0.y); bb.u[2] = f2bf(u0.z); bb.u[3] = f2bf(u0.w);
      bb.u[4] = f2bf(u1.x); bb.u[5] = f2bf(u1.y); bb.u[6] = f2bf(u1.z); bb.u[7] = f2bf(u1.w);
      acc[nt] = __builtin_amdgcn_mfma_f32_16x16x32_bf16(a, bb.v, acc[nt], 0, 0, 0);
    }
  }

  float g4[4];
#pragma unroll
  for (int r = 0; r < 4; ++r) g4[r] = ga[kg * 4 + r];
  float* pp = part + ((size_t)ks * 240 + rt * 16) * ODIM;
#pragma unroll
  for (int nt = 0; nt < 2; ++nt) {
    int o = ot * 128 + w * 32 + nt * 16 + m;
#pragma unroll
    for (int r = 0; r < 4; ++r)
      pp[(kg * 4 + r) * ODIM + o] = acc[nt][r] * g4[r];
  }
}

// ---------------------------------------------------------------------------
// K4: 1024 threads/block -- the 32-partial sum is split 4-way (8 loads per
// thread instead of 32) and combined in LDS. Same traffic, 4x shorter
// latency chain.
// ---------------------------------------------------------------------------
__global__ __launch_bounds__(1024) void k4_out(
    const float* __restrict__ part, const float* __restrict__ bias,
    float* __restrict__ out)
{
  __shared__ float acc[4][256];
  __shared__ float red[4];
  const int r = blockIdx.x;
  const int t = threadIdx.x;
  const int o = t & 255, sq = t >> 8;

  float v = 0.f;
#pragma unroll
  for (int s = 0; s < 8; ++s)
    v += part[((size_t)(sq * 8 + s) * 240 + r) * ODIM + o];
  acc[sq][o] = v;
  __syncthreads();

  float ss = 0.f;
  if (t < 256) {
    v = acc[0][o] + acc[1][o] + acc[2][o] + acc[3][o] + bias[o];
    ss = v * v;
    ss += __shfl_xor(ss, 32);
    ss += __shfl_xor(ss, 16);
    ss += __shfl_xor(ss, 8);
    ss += __shfl_xor(ss, 4);
    ss += __shfl_xor(ss, 2);
    ss += __shfl_xor(ss, 1);
    if ((t & 63) == 0) red[t >> 6] = ss;
  }
  __syncthreads();
  if (t < 256) {
    float total = red[0] + red[1] + red[2] + red[3];
    out[(size_t)r * ODIM + o] = v / fmaxf(sqrtf(total), EPSF);
  }
}

// ---------------------------------------------------------------------------
extern "C" void kernel_launch(void* const* d_in, const int* in_sizes, int n_in,
                              void* d_out, int out_size, void* d_ws, size_t ws_size,
                              hipStream_t stream) {
  const float* x       = (const float*)d_in[0];
  const float* centers = (const float*)d_in[1];
  const float* conv_w  = (const float*)d_in[2];
  const float* conv_b  = (const float*)d_in[3];
  const float* mlp_w   = (const float*)d_in[4];
  const float* mlp_b   = (const float*)d_in[5];
  float* out = (float*)d_out;

  float* ws     = (float*)d_ws;
  float* P      = ws;                       // 5,898,240 floats (23.6 MB)
  float* PA     = ws + 5898240;             // 46,080 floats
  u16*   vlad16 = (u16*)(ws + 5944320);     // 240*8192 u16 (3.9 MB)
  float* gss    = (float*)(ws + 6927360);   // 240*8 floats
  float* part   = ws;                       // [32][240][256] overlays dead P

  k1_assign<<<dim3(8 * NCB),    dim3(256),  0, stream>>>(x, conv_w, conv_b, P, PA);
  k2_vlad  <<<dim3(8 * NT * 8), dim3(256),  0, stream>>>(P, PA, centers, vlad16, gss);
  k3_gemm  <<<dim3(960),        dim3(256),  0, stream>>>(vlad16, gss, mlp_w, part);
  k4_out   <<<dim3(240),        dim3(1024), 0, stream>>>(part, mlp_b, out);
}

// Round 6
// 172.223 us; speedup vs baseline: 1.4357x; 1.0010x over previous
//
#include <hip/hip_runtime.h>
#include <cstddef>

#define EPSF 1e-12f
#define NCB 90
#define NT 30
#define ODIM 256
#define DDIM 8192

typedef unsigned short u16;
typedef __attribute__((ext_vector_type(8))) short short8;
typedef __attribute__((ext_vector_type(4))) float float4v;

__device__ inline u16 f2bf(float f) {
  union { float f; unsigned u; } v; v.f = f;
  unsigned r = v.u + 0x7FFFu + ((v.u >> 16) & 1u);
  return (u16)(r >> 16);
}
__device__ inline float bf2f(u16 h) {
  union { unsigned u; float f; } v; v.u = ((unsigned)h) << 16;
  return v.f;
}

// ---------------------------------------------------------------------------
// K1 (MFMA): EXACT R0 form (measured 55.5us, 83 MB, no spill at VGPR=84).
// Every higher-concurrency variant spilled or blew the per-XCD L2 working
// set (traffic x3.5). Do not touch.
// ---------------------------------------------------------------------------
__global__ __launch_bounds__(256, 3) void k1_assign(
    const float* __restrict__ x,       // [8][128][16][900]
    const float* __restrict__ conv_w,  // [64][128]
    const float* __restrict__ conv_b,  // [64]
    float* __restrict__ P,             // [8][90][64][128]
    float* __restrict__ PA)            // [8][90][64]
{
  __shared__ u16 xtf[4160];        // logits A-frags: F*520 + lane*8 + j
  __shared__ u16 xf[5120];         // P B-frags: ct*640 + (lane>>4)*160 + (lane&15)*8 + j
  __shared__ float As[64 * 33];    // logits -> exp
  __shared__ u16 afr[2048];        // a frags
  __shared__ float invs[32];       // 1/sum per column
  __shared__ float pasum[256];

  const int bx0 = blockIdx.x;
  const int id = (bx0 & 7) * 90 + (bx0 >> 3);   // XCD pin: n = bx0&7
  const int n = id / NCB, cb = id - n * NCB;
  const int t = threadIdx.x;
  const int lane = t & 63;
  const int w = t >> 6;            // wave 0..3

  const float* xn = x + (size_t)n * 1843200 + cb * 10;

  const int colt = w & 1;
  const int kt0 = w >> 1;
  const float bk0 = conv_b[kt0 * 16 + (lane & 15)];
  const float bk1 = conv_b[(kt0 + 2) * 16 + (lane & 15)];

  short8 w0h[4], w0l[4], w1h[4], w1l[4];
  {
    int kr0 = kt0 * 16 + (lane & 15);
    int kr1 = kr0 + 32;
    int cbase = (lane >> 4) << 3;
#pragma unroll
    for (int cb32 = 0; cb32 < 4; ++cb32) {
      const float* wp0 = conv_w + (size_t)kr0 * 128 + cb32 * 32 + cbase;
      const float* wp1 = conv_w + (size_t)kr1 * 128 + cb32 * 32 + cbase;
      union { u16 u[8]; short8 v; } hh, ll;
#pragma unroll
      for (int j = 0; j < 8; ++j) {
        float fv = wp0[j];
        u16 h = f2bf(fv);
        hh.u[j] = h;
        ll.u[j] = f2bf(fv - bf2f(h));
      }
      w0h[cb32] = hh.v; w0l[cb32] = ll.v;
#pragma unroll
      for (int j = 0; j < 8; ++j) {
        float fv = wp1[j];
        u16 h = f2bf(fv);
        hh.u[j] = h;
        ll.u[j] = f2bf(fv - bf2f(h));
      }
      w1h[cb32] = hh.v; w1l[cb32] = ll.v;
    }
  }

  float4v pacc[8];
#pragma unroll
  for (int i = 0; i < 8; ++i) pacc[i] = (float4v){0.f, 0.f, 0.f, 0.f};
  float pak = 0.f;

  // ---- prologue: load cc=0 x into registers ----
  float2 xr[8];
#pragma unroll
  for (int s = 0; s < 8; ++s) {
    int e2 = t + 256 * s;
    int c = e2 >> 4, p = e2 & 15;
    int cl = 2 * p;
    int h = cl / 10, wi = cl - 10 * h;
    xr[s] = *(const float2*)(xn + (size_t)c * 14400 + h * 900 + wi);
  }

  for (int cc = 0; cc < 5; ++cc) {
    __syncthreads();                     // prev P-mfma done before restaging
    // ---- write prefetched regs to both LDS layouts ----
#pragma unroll
    for (int s = 0; s < 8; ++s) {
      int e2 = t + 256 * s;
      int c = e2 >> 4, p = e2 & 15;
      int cl = 2 * p;
      u16 h0 = f2bf(xr[s].x), h1 = f2bf(xr[s].y);
      int ip = (c >> 4) * 640 + (p >> 2) * 160 + (c & 15) * 8 + (cl & 7);
      ushort2 pr; pr.x = h0; pr.y = h1;
      *(ushort2*)&xf[ip] = pr;
      int F = (p >> 3) * 4 + (c >> 5);
      int L = (((c >> 3) & 3) << 4) + (cl & 15);
      int i0 = F * 520 + L * 8 + (c & 7);
      xtf[i0] = h0;
      xtf[i0 + 8] = h1;
    }
    // ---- issue next cc's loads; they retire behind this cc's compute ----
    if (cc < 4) {
#pragma unroll
      for (int s = 0; s < 8; ++s) {
        int e2 = t + 256 * s;
        int c = e2 >> 4, p = e2 & 15;
        int g = (cc + 1) * 32 + 2 * p;
        int h = g / 10, wi = g - 10 * h;
        xr[s] = *(const float2*)(xn + (size_t)c * 14400 + h * 900 + wi);
      }
    }
    __syncthreads();

    // ---- logits MFMA ----
    {
      float4v d0 = (float4v){0.f, 0.f, 0.f, 0.f};
      float4v d1 = (float4v){0.f, 0.f, 0.f, 0.f};
#pragma unroll
      for (int cb32 = 0; cb32 < 4; ++cb32) {
        short8 xa = *(short8*)&xtf[(colt * 4 + cb32) * 520 + lane * 8];
        d0 = __builtin_amdgcn_mfma_f32_16x16x32_bf16(xa, w0h[cb32], d0, 0, 0, 0);
        d0 = __builtin_amdgcn_mfma_f32_16x16x32_bf16(xa, w0l[cb32], d0, 0, 0, 0);
        d1 = __builtin_amdgcn_mfma_f32_16x16x32_bf16(xa, w1h[cb32], d1, 0, 0, 0);
        d1 = __builtin_amdgcn_mfma_f32_16x16x32_bf16(xa, w1l[cb32], d1, 0, 0, 0);
      }
      int colb = colt * 16 + ((lane >> 4) << 2);
      int kr0 = kt0 * 16 + (lane & 15);
      int kr1 = kr0 + 32;
#pragma unroll
      for (int r = 0; r < 4; ++r) {
        As[kr0 * 33 + colb + r] = d0[r] + bk0;
        As[kr1 * 33 + colb + r] = d1[r] + bk1;
      }
    }
    __syncthreads();

    // ---- wave-local softmax over k for cols [8w, 8w+8) ----
    {
      const int col8 = lane & 7;
      const int kq = lane >> 3;
      const int colg = w * 8 + col8;
      float m = -3.4e38f;
#pragma unroll
      for (int i = 0; i < 8; ++i) m = fmaxf(m, As[(kq * 8 + i) * 33 + colg]);
      m = fmaxf(m, __shfl_xor(m, 8));
      m = fmaxf(m, __shfl_xor(m, 16));
      m = fmaxf(m, __shfl_xor(m, 32));
      float s = 0.f;
#pragma unroll
      for (int i = 0; i < 8; ++i) {
        int a = (kq * 8 + i) * 33 + colg;
        float e = __expf(As[a] - m);
        As[a] = e;
        s += e;
      }
      s += __shfl_xor(s, 8);
      s += __shfl_xor(s, 16);
      s += __shfl_xor(s, 32);
      if (kq == 0) invs[w * 8 + col8] = 1.f / s;
    }
    // ---- a-frag build (same wave, no barrier needed) ----
    {
      union { u16 u[8]; short8 v; } cvt;
      float paks = 0.f;
#pragma unroll
      for (int j = 0; j < 8; ++j) {
        float a = As[lane * 33 + w * 8 + j] * invs[w * 8 + j];
        paks += a;
        cvt.u[j] = f2bf(a);
      }
      pak += paks;
      int dst = ((lane >> 4) * 64 + (w << 4) + (lane & 15)) * 8;
      *(short8*)&afr[dst] = cvt.v;
    }
    __syncthreads();

    // ---- P MFMA: wave w owns kt = w; 8 c-tiles ----
    {
      short8 aa = *(short8*)&afr[(w * 64 + lane) * 8];
#pragma unroll
      for (int ct = 0; ct < 8; ++ct) {
        short8 xb = *(short8*)&xf[ct * 640 + (lane >> 4) * 160 + (lane & 15) * 8];
        pacc[ct] = __builtin_amdgcn_mfma_f32_16x16x32_bf16(aa, xb, pacc[ct], 0, 0, 0);
      }
    }
  }

  float* Pp = P + (size_t)(n * NCB + cb) * DDIM;
  {
    int krow = w * 16 + ((lane >> 4) << 2);
    int c0 = lane & 15;
#pragma unroll
    for (int ct = 0; ct < 8; ++ct)
#pragma unroll
      for (int r = 0; r < 4; ++r)
        Pp[(krow + r) * 128 + ct * 16 + c0] = pacc[ct][r];
  }
  pasum[t] = pak;
  __syncthreads();
  if (t < 64)
    PA[(size_t)(n * NCB + cb) * 64 + t] =
        pasum[t] + pasum[64 + t] + pasum[128 + t] + pasum[192 + t];
}

// ---------------------------------------------------------------------------
// K2: R5 form (== R0 perf). 1920 blocks, eb split 8. Traffic-insensitive per
// R4/R5 eliminations -- at its fixed floor; leave alone.
// ---------------------------------------------------------------------------
__global__ __launch_bounds__(256) void k2_vlad(
    const float* __restrict__ P, const float* __restrict__ PA,
    const float* __restrict__ centers, u16* __restrict__ vlad16,
    float* __restrict__ gss)            // [240][8]
{
  __shared__ float Ak[8];
  __shared__ float red[4];
  const int bx0 = blockIdx.x;                    // [0,1920)
  const int id = (bx0 & 7) * 240 + (bx0 >> 3);   // XCD pin: n = bx0&7
  const int n = id / 240;
  const int rem = id - n * 240;
  const int wt = rem >> 3, eb = rem & 7;
  const int win = n * NT + wt;
  const int t = threadIdx.x;

  if (t < 32) {
    int kk = t >> 2, ii = t & 3;
    float s = 0.f;
#pragma unroll
    for (int ss = 0; ss < 5; ++ss) {
      int i = ii + 4 * ss;
      int cb = (3 * wt + 80 + i) % 90;
      s += PA[((size_t)n * NCB + cb) * 64 + eb * 8 + kk];
    }
    s += __shfl_xor(s, 1);
    s += __shfl_xor(s, 2);
    if (ii == 0) Ak[kk] = s;
  }
  __syncthreads();

  const int e0 = eb * 1024 + t * 4;     // global (k,c) offset in [0,8192)
  const float* base = P + (size_t)n * NCB * DDIM + e0;
  float v[4];
#pragma unroll
  for (int j = 0; j < 4; ++j) v[j] = 0.f;
#pragma unroll 5
  for (int i = 0; i < 20; ++i) {
    int cb = (3 * wt + 80 + i) % 90;
    float4 u0 = *(const float4*)(base + (size_t)cb * DDIM);
    v[0] += u0.x; v[1] += u0.y; v[2] += u0.z; v[3] += u0.w;
  }

  const float A = Ak[t >> 5];           // k_local = t/32
  const float* ce = centers + e0;
  float ss8 = 0.f;
#pragma unroll
  for (int j = 0; j < 4; ++j) {
    float val = v[j] - ce[j] * A;
    v[j] = val;
    ss8 += val * val;
  }
  // per-k (32-thread group) reduction for intra-norm
  float ssg = ss8;
  ssg += __shfl_xor(ssg, 1);
  ssg += __shfl_xor(ssg, 2);
  ssg += __shfl_xor(ssg, 4);
  ssg += __shfl_xor(ssg, 8);
  ssg += __shfl_xor(ssg, 16);
  float rn = 1.f / fmaxf(sqrtf(ssg), EPSF);
  // block-wide sum of normalized squares (for global norm)
  float ts = ss8 * rn * rn;
  ts += __shfl_xor(ts, 1);
  ts += __shfl_xor(ts, 2);
  ts += __shfl_xor(ts, 4);
  ts += __shfl_xor(ts, 8);
  ts += __shfl_xor(ts, 16);
  ts += __shfl_xor(ts, 32);
  if ((t & 63) == 0) red[t >> 6] = ts;
  __syncthreads();
  if (t == 0) gss[(size_t)win * 8 + eb] = red[0] + red[1] + red[2] + red[3];

  union { u16 u[4]; ushort4 v4; } o;
#pragma unroll
  for (int j = 0; j < 4; ++j) o.u[j] = f2bf(v[j] * rn);
  *(ushort4*)(vlad16 + (size_t)win * DDIM + e0) = o.v4;
}

// ---------------------------------------------------------------------------
// K3 (MFMA, RESTRUCTURED): each block computes 3 rt-tiles (M=48), reusing
// every loaded+converted weight fragment 3x. Weight traffic 125 -> 42 MB;
// conversion VALU per MFMA / 3. XCD pin: the 5 rtg-blocks sharing one
// (ks,ot) weight slice land on the same XCD (per-XCD weight set ~1 MB,
// L2-resident -> HBM-side weight reads approach read-once, 8.4 MB).
// Per-output MFMA chain order unchanged -> bit-identical part.
// ---------------------------------------------------------------------------
__global__ __launch_bounds__(256) void k3_gemm(
    const u16* __restrict__ vlad16, const float* __restrict__ gss,
    const float* __restrict__ mlp_w, float* __restrict__ part)
{
  __shared__ float ga[48];
  const int bx = blockIdx.x;         // [0,320)
  const int xcd = bx & 7;
  const int q = bx >> 3;             // [0,40)
  const int rtg = q % 5;             // rt-group: rows [rtg*48, rtg*48+48)
  const int h = (q / 5) * 8 + xcd;   // [0,64): same h -> same XCD, adjacent
  const int ot = h & 1;              // o half
  const int ks = h >> 1;             // K-slice of 256
  const int t = threadIdx.x;
  const int lane = t & 63;
  const int w = t >> 6;

  if (t < 48) {
    int r = rtg * 48 + t;
    float s = 0.f;
#pragma unroll
    for (int j = 0; j < 8; ++j) s += gss[(size_t)r * 8 + j];
    ga[t] = 1.f / fmaxf(sqrtf(s), EPSF);
  }
  __syncthreads();

  const int m = lane & 15;
  const int kg = lane >> 4;
  const int d0 = ks * 256 + kg * 8;
  const u16* a0 = vlad16 + (size_t)(rtg * 48 + m) * DDIM + d0;

  float4v acc[3][2];
#pragma unroll
  for (int mi = 0; mi < 3; ++mi)
#pragma unroll
    for (int i = 0; i < 2; ++i) acc[mi][i] = (float4v){0.f, 0.f, 0.f, 0.f};

#pragma unroll
  for (int ko = 0; ko < 8; ++ko) {
    short8 a[3];
#pragma unroll
    for (int mi = 0; mi < 3; ++mi)
      a[mi] = *(const short8*)(a0 + (size_t)(mi * 16) * DDIM + ko * 32);
#pragma unroll
    for (int nt = 0; nt < 2; ++nt) {
      int o = ot * 128 + w * 32 + nt * 16 + m;
      const float* wrow = mlp_w + (size_t)o * DDIM + d0 + ko * 32;
      float4 u0 = *(const float4*)wrow;
      float4 u1 = *(const float4*)(wrow + 4);
      union { u16 u[8]; short8 v; } bb;
      bb.u[0] = f2bf(u0.x); bb.u[1] = f2bf(u0.y); bb.u[2] = f2bf(u0.z); bb.u[3] = f2bf(u0.w);
      bb.u[4] = f2bf(u1.x); bb.u[5] = f2bf(u1.y); bb.u[6] = f2bf(u1.z); bb.u[7] = f2bf(u1.w);
#pragma unroll
      for (int mi = 0; mi < 3; ++mi)
        acc[mi][nt] = __builtin_amdgcn_mfma_f32_16x16x32_bf16(a[mi], bb.v, acc[mi][nt], 0, 0, 0);
    }
  }

  float* pp = part + ((size_t)ks * 240 + rtg * 48) * ODIM;
#pragma unroll
  for (int mi = 0; mi < 3; ++mi)
#pragma unroll
    for (int nt = 0; nt < 2; ++nt) {
      int o = ot * 128 + w * 32 + nt * 16 + m;
#pragma unroll
      for (int r = 0; r < 4; ++r) {
        int rl = mi * 16 + kg * 4 + r;
        pp[rl * ODIM + o] = acc[mi][nt][r] * ga[rl];
      }
    }
}

// ---------------------------------------------------------------------------
// K4: R5 form (1024 threads, 4-way split sum). At its fixed floor.
// ---------------------------------------------------------------------------
__global__ __launch_bounds__(1024) void k4_out(
    const float* __restrict__ part, const float* __restrict__ bias,
    float* __restrict__ out)
{
  __shared__ float acc[4][256];
  __shared__ float red[4];
  const int r = blockIdx.x;
  const int t = threadIdx.x;
  const int o = t & 255, sq = t >> 8;

  float v = 0.f;
#pragma unroll
  for (int s = 0; s < 8; ++s)
    v += part[((size_t)(sq * 8 + s) * 240 + r) * ODIM + o];
  acc[sq][o] = v;
  __syncthreads();

  float ss = 0.f;
  if (t < 256) {
    v = acc[0][o] + acc[1][o] + acc[2][o] + acc[3][o] + bias[o];
    ss = v * v;
    ss += __shfl_xor(ss, 32);
    ss += __shfl_xor(ss, 16);
    ss += __shfl_xor(ss, 8);
    ss += __shfl_xor(ss, 4);
    ss += __shfl_xor(ss, 2);
    ss += __shfl_xor(ss, 1);
    if ((t & 63) == 0) red[t >> 6] = ss;
  }
  __syncthreads();
  if (t < 256) {
    float total = red[0] + red[1] + red[2] + red[3];
    out[(size_t)r * ODIM + o] = v / fmaxf(sqrtf(total), EPSF);
  }
}

// ---------------------------------------------------------------------------
extern "C" void kernel_launch(void* const* d_in, const int* in_sizes, int n_in,
                              void* d_out, int out_size, void* d_ws, size_t ws_size,
                              hipStream_t stream) {
  const float* x       = (const float*)d_in[0];
  const float* centers = (const float*)d_in[1];
  const float* conv_w  = (const float*)d_in[2];
  const float* conv_b  = (const float*)d_in[3];
  const float* mlp_w   = (const float*)d_in[4];
  const float* mlp_b   = (const float*)d_in[5];
  float* out = (float*)d_out;

  float* ws     = (float*)d_ws;
  float* P      = ws;                       // 5,898,240 floats (23.6 MB)
  float* PA     = ws + 5898240;             // 46,080 floats
  u16*   vlad16 = (u16*)(ws + 5944320);     // 240*8192 u16 (3.9 MB)
  float* gss    = (float*)(ws + 6927360);   // 240*8 floats
  float* part   = ws;                       // [32][240][256] overlays dead P

  k1_assign<<<dim3(8 * NCB),    dim3(256),  0, stream>>>(x, conv_w, conv_b, P, PA);
  k2_vlad  <<<dim3(8 * NT * 8), dim3(256),  0, stream>>>(P, PA, centers, vlad16, gss);
  k3_gemm  <<<dim3(320),        dim3(256),  0, stream>>>(vlad16, gss, mlp_w, part);
  k4_out   <<<dim3(240),        dim3(1024), 0, stream>>>(part, mlp_b, out);
}

// Round 7
// 161.713 us; speedup vs baseline: 1.5290x; 1.0650x over previous
//
#include <hip/hip_runtime.h>
#include <cstddef>

#define EPSF 1e-12f
#define NCB 90
#define NT 30
#define ODIM 256
#define DDIM 8192

typedef unsigned short u16;
typedef __attribute__((ext_vector_type(8))) short short8;
typedef __attribute__((ext_vector_type(4))) float float4v;

__device__ inline u16 f2bf(float f) {
  union { float f; unsigned u; } v; v.f = f;
  unsigned r = v.u + 0x7FFFu + ((v.u >> 16) & 1u);
  return (u16)(r >> 16);
}
__device__ inline float bf2f(u16 h) {
  union { unsigned u; float f; } v; v.u = ((unsigned)h) << 16;
  return v.f;
}

// ---------------------------------------------------------------------------
// K1 (MFMA): R2's 8-wave structure (passed correctness; 2.75 TB/s effective
// BW = 1.8x the 4-wave form) with the spill fixed: launch_bounds(512,2)
// instead of (512,6). R2's VGPR_Count=40 + WRITE_SIZE 142MB was pure scratch
// spill from the forced <=42 VGPR budget; the kernel needs ~90. Same 720
// blocks, same x-read-once / whole-P-row dataflow as the 55us form, but
// half the per-wave critical path and ~16 resident waves/CU vs 11.2.
// ---------------------------------------------------------------------------
__global__ __launch_bounds__(512, 2) void k1_assign(
    const float* __restrict__ x,       // [8][128][16][900]
    const float* __restrict__ conv_w,  // [64][128]
    const float* __restrict__ conv_b,  // [64]
    float* __restrict__ P,             // [8][90][64][128]
    float* __restrict__ PA)            // [8][90][64]
{
  __shared__ u16 xtf[4160];        // logits A-frags: F*520 + lane*8 + j
  __shared__ u16 xf[5120];         // P B-frags: ct*640 + (lane>>4)*160 + (lane&15)*8 + j
  __shared__ float As[64 * 33];    // logits -> exp
  __shared__ u16 afr[2048];        // a frags
  __shared__ float invs[32];       // 1/sum per column
  __shared__ float pasum[512];

  const int bx0 = blockIdx.x;      // [0,720)
  const int n = bx0 & 7;           // XCD pin
  const int cb = bx0 >> 3;
  const int t = threadIdx.x;
  const int lane = t & 63;
  const int w8 = t >> 6;           // wave 0..7

  const float* xn = x + (size_t)n * 1843200 + cb * 10;

  const int colt = w8 & 1;         // logits column tile
  const int kt = w8 >> 1;          // k-tile 0..3
  const int kr = kt * 16 + (lane & 15);
  const float bk = conv_b[kr];

  short8 wh[4], wl[4];
  {
    const int cbase = (lane >> 4) << 3;
#pragma unroll
    for (int cb32 = 0; cb32 < 4; ++cb32) {
      const float* wp = conv_w + (size_t)kr * 128 + cb32 * 32 + cbase;
      float4 u0 = *(const float4*)wp;
      float4 u1 = *(const float4*)(wp + 4);
      float fv[8] = {u0.x, u0.y, u0.z, u0.w, u1.x, u1.y, u1.z, u1.w};
      union { u16 u[8]; short8 v; } hh, ll;
#pragma unroll
      for (int j = 0; j < 8; ++j) {
        u16 h = f2bf(fv[j]);
        hh.u[j] = h;
        ll.u[j] = f2bf(fv[j] - bf2f(h));
      }
      wh[cb32] = hh.v; wl[cb32] = ll.v;
    }
  }

  float4v pacc[4];
#pragma unroll
  for (int i = 0; i < 4; ++i) pacc[i] = (float4v){0.f, 0.f, 0.f, 0.f};
  float pak = 0.f;

  // ---- prologue: load cc=0 x into registers ----
  float2 xr[4];
#pragma unroll
  for (int s = 0; s < 4; ++s) {
    int e2 = t + 512 * s;
    int c = e2 >> 4, p = e2 & 15;
    int cl = 2 * p;
    int h = cl / 10, wi = cl - 10 * h;
    xr[s] = *(const float2*)(xn + (size_t)c * 14400 + h * 900 + wi);
  }

  for (int cc = 0; cc < 5; ++cc) {
    __syncthreads();                     // prev P-mfma done before restaging
    // ---- write prefetched regs to both LDS layouts ----
#pragma unroll
    for (int s = 0; s < 4; ++s) {
      int e2 = t + 512 * s;
      int c = e2 >> 4, p = e2 & 15;
      int cl = 2 * p;
      u16 h0 = f2bf(xr[s].x), h1 = f2bf(xr[s].y);
      int ip = (c >> 4) * 640 + (p >> 2) * 160 + (c & 15) * 8 + (cl & 7);
      ushort2 pr; pr.x = h0; pr.y = h1;
      *(ushort2*)&xf[ip] = pr;
      int F = (p >> 3) * 4 + (c >> 5);
      int L = (((c >> 3) & 3) << 4) + (cl & 15);
      int i0 = F * 520 + L * 8 + (c & 7);
      xtf[i0] = h0;
      xtf[i0 + 8] = h1;
    }
    // ---- issue next cc's loads; they retire behind this cc's compute ----
    if (cc < 4) {
#pragma unroll
      for (int s = 0; s < 4; ++s) {
        int e2 = t + 512 * s;
        int c = e2 >> 4, p = e2 & 15;
        int g = (cc + 1) * 32 + 2 * p;
        int h = g / 10, wi = g - 10 * h;
        xr[s] = *(const float2*)(xn + (size_t)c * 14400 + h * 900 + wi);
      }
    }
    __syncthreads();

    // ---- logits MFMA: wave (colt, kt) computes 16 k-rows x 16 cols ----
    {
      float4v d0 = (float4v){0.f, 0.f, 0.f, 0.f};
#pragma unroll
      for (int cb32 = 0; cb32 < 4; ++cb32) {
        short8 xa = *(short8*)&xtf[(colt * 4 + cb32) * 520 + lane * 8];
        d0 = __builtin_amdgcn_mfma_f32_16x16x32_bf16(xa, wh[cb32], d0, 0, 0, 0);
        d0 = __builtin_amdgcn_mfma_f32_16x16x32_bf16(xa, wl[cb32], d0, 0, 0, 0);
      }
      int colb = colt * 16 + ((lane >> 4) << 2);
#pragma unroll
      for (int r = 0; r < 4; ++r)
        As[kr * 33 + colb + r] = d0[r] + bk;
    }
    __syncthreads();

    // ---- wave-local softmax over k for cols [4*w8, 4*w8+4) ----
    {
      const int col4 = lane & 3;
      const int kq = lane >> 2;          // 16 groups of 4 k
      const int colg = w8 * 4 + col4;
      float m = -3.4e38f;
#pragma unroll
      for (int i = 0; i < 4; ++i) m = fmaxf(m, As[(kq * 4 + i) * 33 + colg]);
      m = fmaxf(m, __shfl_xor(m, 4));
      m = fmaxf(m, __shfl_xor(m, 8));
      m = fmaxf(m, __shfl_xor(m, 16));
      m = fmaxf(m, __shfl_xor(m, 32));
      float s = 0.f;
#pragma unroll
      for (int i = 0; i < 4; ++i) {
        int a = (kq * 4 + i) * 33 + colg;
        float e = __expf(As[a] - m);
        As[a] = e;
        s += e;
      }
      s += __shfl_xor(s, 4);
      s += __shfl_xor(s, 8);
      s += __shfl_xor(s, 16);
      s += __shfl_xor(s, 32);
      if (kq == 0) invs[colg] = 1.f / s;
    }
    // ---- a-frag build (same wave's columns, no barrier needed) ----
    {
      union { u16 u[4]; ushort4 v; } cvt;
      float paks = 0.f;
#pragma unroll
      for (int j = 0; j < 4; ++j) {
        float a = As[lane * 33 + w8 * 4 + j] * invs[w8 * 4 + j];
        paks += a;
        cvt.u[j] = f2bf(a);
      }
      pak += paks;
      int dst = ((lane >> 4) * 64 + ((w8 >> 1) << 4) + (lane & 15)) * 8 + (w8 & 1) * 4;
      *(ushort4*)&afr[dst] = cvt.v;
    }
    __syncthreads();

    // ---- P MFMA: wave (kt, w8&1) owns k-tile kt, 4 of 8 c-tiles ----
    {
      short8 aa = *(short8*)&afr[((w8 >> 1) * 64 + lane) * 8];
#pragma unroll
      for (int c4 = 0; c4 < 4; ++c4) {
        int ct = (w8 & 1) * 4 + c4;
        short8 xb = *(short8*)&xf[ct * 640 + (lane >> 4) * 160 + (lane & 15) * 8];
        pacc[c4] = __builtin_amdgcn_mfma_f32_16x16x32_bf16(aa, xb, pacc[c4], 0, 0, 0);
      }
    }
  }

  float* Pp = P + (size_t)(n * NCB + cb) * DDIM;
  {
    int krow = (w8 >> 1) * 16 + ((lane >> 4) << 2);
    int c0 = (w8 & 1) * 64 + (lane & 15);
#pragma unroll
    for (int c4 = 0; c4 < 4; ++c4)
#pragma unroll
      for (int r = 0; r < 4; ++r)
        Pp[(krow + r) * 128 + c0 + c4 * 16] = pacc[c4][r];
  }
  pasum[t] = pak;
  __syncthreads();
  if (t < 64) {
    float s = 0.f;
#pragma unroll
    for (int i = 0; i < 8; ++i) s += pasum[t + 64 * i];
    PA[(size_t)(n * NCB + cb) * 64 + t] = s;
  }
}

// ---------------------------------------------------------------------------
// K2: R5/R6 form. Traffic- and TLP-insensitive (R4/R5 eliminations); at its
// floor. Unchanged.
// ---------------------------------------------------------------------------
__global__ __launch_bounds__(256) void k2_vlad(
    const float* __restrict__ P, const float* __restrict__ PA,
    const float* __restrict__ centers, u16* __restrict__ vlad16,
    float* __restrict__ gss)            // [240][8]
{
  __shared__ float Ak[8];
  __shared__ float red[4];
  const int bx0 = blockIdx.x;                    // [0,1920)
  const int id = (bx0 & 7) * 240 + (bx0 >> 3);   // XCD pin: n = bx0&7
  const int n = id / 240;
  const int rem = id - n * 240;
  const int wt = rem >> 3, eb = rem & 7;
  const int win = n * NT + wt;
  const int t = threadIdx.x;

  if (t < 32) {
    int kk = t >> 2, ii = t & 3;
    float s = 0.f;
#pragma unroll
    for (int ss = 0; ss < 5; ++ss) {
      int i = ii + 4 * ss;
      int cb = (3 * wt + 80 + i) % 90;
      s += PA[((size_t)n * NCB + cb) * 64 + eb * 8 + kk];
    }
    s += __shfl_xor(s, 1);
    s += __shfl_xor(s, 2);
    if (ii == 0) Ak[kk] = s;
  }
  __syncthreads();

  const int e0 = eb * 1024 + t * 4;     // global (k,c) offset in [0,8192)
  const float* base = P + (size_t)n * NCB * DDIM + e0;
  float v[4];
#pragma unroll
  for (int j = 0; j < 4; ++j) v[j] = 0.f;
#pragma unroll 5
  for (int i = 0; i < 20; ++i) {
    int cb = (3 * wt + 80 + i) % 90;
    float4 u0 = *(const float4*)(base + (size_t)cb * DDIM);
    v[0] += u0.x; v[1] += u0.y; v[2] += u0.z; v[3] += u0.w;
  }

  const float A = Ak[t >> 5];           // k_local = t/32
  const float* ce = centers + e0;
  float ss8 = 0.f;
#pragma unroll
  for (int j = 0; j < 4; ++j) {
    float val = v[j] - ce[j] * A;
    v[j] = val;
    ss8 += val * val;
  }
  // per-k (32-thread group) reduction for intra-norm
  float ssg = ss8;
  ssg += __shfl_xor(ssg, 1);
  ssg += __shfl_xor(ssg, 2);
  ssg += __shfl_xor(ssg, 4);
  ssg += __shfl_xor(ssg, 8);
  ssg += __shfl_xor(ssg, 16);
  float rn = 1.f / fmaxf(sqrtf(ssg), EPSF);
  // block-wide sum of normalized squares (for global norm)
  float ts = ss8 * rn * rn;
  ts += __shfl_xor(ts, 1);
  ts += __shfl_xor(ts, 2);
  ts += __shfl_xor(ts, 4);
  ts += __shfl_xor(ts, 8);
  ts += __shfl_xor(ts, 16);
  ts += __shfl_xor(ts, 32);
  if ((t & 63) == 0) red[t >> 6] = ts;
  __syncthreads();
  if (t == 0) gss[(size_t)win * 8 + eb] = red[0] + red[1] + red[2] + red[3];

  union { u16 u[4]; ushort4 v4; } o;
#pragma unroll
  for (int j = 0; j < 4; ++j) o.u[j] = f2bf(v[j] * rn);
  *(ushort4*)(vlad16 + (size_t)win * DDIM + e0) = o.v4;
}

// ---------------------------------------------------------------------------
// K3 (MFMA): R6 form (3 rt-tiles per block, XCD-pinned weight slices).
// Unchanged.
// ---------------------------------------------------------------------------
__global__ __launch_bounds__(256) void k3_gemm(
    const u16* __restrict__ vlad16, const float* __restrict__ gss,
    const float* __restrict__ mlp_w, float* __restrict__ part)
{
  __shared__ float ga[48];
  const int bx = blockIdx.x;         // [0,320)
  const int xcd = bx & 7;
  const int q = bx >> 3;             // [0,40)
  const int rtg = q % 5;             // rt-group: rows [rtg*48, rtg*48+48)
  const int h = (q / 5) * 8 + xcd;   // [0,64): same h -> same XCD, adjacent
  const int ot = h & 1;              // o half
  const int ks = h >> 1;             // K-slice of 256
  const int t = threadIdx.x;
  const int lane = t & 63;
  const int w = t >> 6;

  if (t < 48) {
    int r = rtg * 48 + t;
    float s = 0.f;
#pragma unroll
    for (int j = 0; j < 8; ++j) s += gss[(size_t)r * 8 + j];
    ga[t] = 1.f / fmaxf(sqrtf(s), EPSF);
  }
  __syncthreads();

  const int m = lane & 15;
  const int kg = lane >> 4;
  const int d0 = ks * 256 + kg * 8;
  const u16* a0 = vlad16 + (size_t)(rtg * 48 + m) * DDIM + d0;

  float4v acc[3][2];
#pragma unroll
  for (int mi = 0; mi < 3; ++mi)
#pragma unroll
    for (int i = 0; i < 2; ++i) acc[mi][i] = (float4v){0.f, 0.f, 0.f, 0.f};

#pragma unroll
  for (int ko = 0; ko < 8; ++ko) {
    short8 a[3];
#pragma unroll
    for (int mi = 0; mi < 3; ++mi)
      a[mi] = *(const short8*)(a0 + (size_t)(mi * 16) * DDIM + ko * 32);
#pragma unroll
    for (int nt = 0; nt < 2; ++nt) {
      int o = ot * 128 + w * 32 + nt * 16 + m;
      const float* wrow = mlp_w + (size_t)o * DDIM + d0 + ko * 32;
      float4 u0 = *(const float4*)wrow;
      float4 u1 = *(const float4*)(wrow + 4);
      union { u16 u[8]; short8 v; } bb;
      bb.u[0] = f2bf(u0.x); bb.u[1] = f2bf(u0.y); bb.u[2] = f2bf(u0.z); bb.u[3] = f2bf(u0.w);
      bb.u[4] = f2bf(u1.x); bb.u[5] = f2bf(u1.y); bb.u[6] = f2bf(u1.z); bb.u[7] = f2bf(u1.w);
#pragma unroll
      for (int mi = 0; mi < 3; ++mi)
        acc[mi][nt] = __builtin_amdgcn_mfma_f32_16x16x32_bf16(a[mi], bb.v, acc[mi][nt], 0, 0, 0);
    }
  }

  float* pp = part + ((size_t)ks * 240 + rtg * 48) * ODIM;
#pragma unroll
  for (int mi = 0; mi < 3; ++mi)
#pragma unroll
    for (int nt = 0; nt < 2; ++nt) {
      int o = ot * 128 + w * 32 + nt * 16 + m;
#pragma unroll
      for (int r = 0; r < 4; ++r) {
        int rl = mi * 16 + kg * 4 + r;
        pp[rl * ODIM + o] = acc[mi][nt][r] * ga[rl];
      }
    }
}

// ---------------------------------------------------------------------------
// K4: R5/R6 form (1024 threads, 4-way split sum). At its floor. Unchanged.
// ---------------------------------------------------------------------------
__global__ __launch_bounds__(1024) void k4_out(
    const float* __restrict__ part, const float* __restrict__ bias,
    float* __restrict__ out)
{
  __shared__ float acc[4][256];
  __shared__ float red[4];
  const int r = blockIdx.x;
  const int t = threadIdx.x;
  const int o = t & 255, sq = t >> 8;

  float v = 0.f;
#pragma unroll
  for (int s = 0; s < 8; ++s)
    v += part[((size_t)(sq * 8 + s) * 240 + r) * ODIM + o];
  acc[sq][o] = v;
  __syncthreads();

  float ss = 0.f;
  if (t < 256) {
    v = acc[0][o] + acc[1][o] + acc[2][o] + acc[3][o] + bias[o];
    ss = v * v;
    ss += __shfl_xor(ss, 32);
    ss += __shfl_xor(ss, 16);
    ss += __shfl_xor(ss, 8);
    ss += __shfl_xor(ss, 4);
    ss += __shfl_xor(ss, 2);
    ss += __shfl_xor(ss, 1);
    if ((t & 63) == 0) red[t >> 6] = ss;
  }
  __syncthreads();
  if (t < 256) {
    float total = red[0] + red[1] + red[2] + red[3];
    out[(size_t)r * ODIM + o] = v / fmaxf(sqrtf(total), EPSF);
  }
}

// ---------------------------------------------------------------------------
extern "C" void kernel_launch(void* const* d_in, const int* in_sizes, int n_in,
                              void* d_out, int out_size, void* d_ws, size_t ws_size,
                              hipStream_t stream) {
  const float* x       = (const float*)d_in[0];
  const float* centers = (const float*)d_in[1];
  const float* conv_w  = (const float*)d_in[2];
  const float* conv_b  = (const float*)d_in[3];
  const float* mlp_w   = (const float*)d_in[4];
  const float* mlp_b   = (const float*)d_in[5];
  float* out = (float*)d_out;

  float* ws     = (float*)d_ws;
  float* P      = ws;                       // 5,898,240 floats (23.6 MB)
  float* PA     = ws + 5898240;             // 46,080 floats
  u16*   vlad16 = (u16*)(ws + 5944320);     // 240*8192 u16 (3.9 MB)
  float* gss    = (float*)(ws + 6927360);   // 240*8 floats
  float* part   = ws;                       // [32][240][256] overlays dead P

  k1_assign<<<dim3(8 * NCB),    dim3(512),  0, stream>>>(x, conv_w, conv_b, P, PA);
  k2_vlad  <<<dim3(8 * NT * 8), dim3(256),  0, stream>>>(P, PA, centers, vlad16, gss);
  k3_gemm  <<<dim3(320),        dim3(256),  0, stream>>>(vlad16, gss, mlp_w, part);
  k4_out   <<<dim3(240),        dim3(1024), 0, stream>>>(part, mlp_b, out);
}

// Round 8
// 161.614 us; speedup vs baseline: 1.5300x; 1.0006x over previous
//
#include <hip/hip_runtime.h>
#include <cstddef>

#define EPSF 1e-12f
#define NCB 90
#define NT 30
#define ODIM 256
#define DDIM 8192

typedef unsigned short u16;
typedef __attribute__((ext_vector_type(8))) short short8;
typedef __attribute__((ext_vector_type(4))) float float4v;

__device__ inline u16 f2bf(float f) {
  union { float f; unsigned u; } v; v.f = f;
  unsigned r = v.u + 0x7FFFu + ((v.u >> 16) & 1u);
  return (u16)(r >> 16);
}
__device__ inline float bf2f(u16 h) {
  union { unsigned u; float f; } v; v.u = ((unsigned)h) << 16;
  return v.f;
}

// ---------------------------------------------------------------------------
// K1 (MFMA): R7's 8-wave form (46us) + double-buffered staging LDS. The
// staging phase (load-drain + f2bf + LDS writes) no longer occupies its own
// barrier-bounded slot: writes for cc+1 go to the idle buffer DURING the
// P-MFMA phase of cc, and loads for cc+2 issue right after (latency covered
// by logits+softmax of cc+1). Barriers stay 3/cc but the serial content
// between them shrinks by the whole staging phase. LDS 51.8KB -> still
// 3 blocks/CU >= grid's 2.8. P/PA math and write pattern bit-identical.
// ---------------------------------------------------------------------------
__global__ __launch_bounds__(512, 2) void k1_assign(
    const float* __restrict__ x,       // [8][128][16][900]
    const float* __restrict__ conv_w,  // [64][128]
    const float* __restrict__ conv_b,  // [64]
    float* __restrict__ P,             // [8][90][64][128]
    float* __restrict__ PA)            // [8][90][64]
{
  __shared__ u16 xtf[2][4160];     // logits A-frags (dbuf): F*520 + lane*8 + j
  __shared__ u16 xf[2][5120];      // P B-frags (dbuf): ct*640 + (lane>>4)*160 + (lane&15)*8 + j
  __shared__ float As[64 * 33];    // logits -> exp
  __shared__ u16 afr[2048];        // a frags
  __shared__ float invs[32];       // 1/sum per column
  __shared__ float pasum[512];

  const int bx0 = blockIdx.x;      // [0,720)
  const int n = bx0 & 7;           // XCD pin
  const int cb = bx0 >> 3;
  const int t = threadIdx.x;
  const int lane = t & 63;
  const int w8 = t >> 6;           // wave 0..7

  const float* xn = x + (size_t)n * 1843200 + cb * 10;

  const int colt = w8 & 1;         // logits column tile
  const int kt = w8 >> 1;          // k-tile 0..3
  const int kr = kt * 16 + (lane & 15);
  const float bk = conv_b[kr];

  short8 wh[4], wl[4];
  {
    const int cbase = (lane >> 4) << 3;
#pragma unroll
    for (int cb32 = 0; cb32 < 4; ++cb32) {
      const float* wp = conv_w + (size_t)kr * 128 + cb32 * 32 + cbase;
      float4 u0 = *(const float4*)wp;
      float4 u1 = *(const float4*)(wp + 4);
      float fv[8] = {u0.x, u0.y, u0.z, u0.w, u1.x, u1.y, u1.z, u1.w};
      union { u16 u[8]; short8 v; } hh, ll;
#pragma unroll
      for (int j = 0; j < 8; ++j) {
        u16 h = f2bf(fv[j]);
        hh.u[j] = h;
        ll.u[j] = f2bf(fv[j] - bf2f(h));
      }
      wh[cb32] = hh.v; wl[cb32] = ll.v;
    }
  }

  float4v pacc[4];
#pragma unroll
  for (int i = 0; i < 4; ++i) pacc[i] = (float4v){0.f, 0.f, 0.f, 0.f};
  float pak = 0.f;

  float2 xr[4];
  // ---- prologue: load cc=0, stage into buf 0, then issue loads for cc=1 ----
#pragma unroll
  for (int s = 0; s < 4; ++s) {
    int e2 = t + 512 * s;
    int c = e2 >> 4, p = e2 & 15;
    int cl = 2 * p;
    int h = cl / 10, wi = cl - 10 * h;
    xr[s] = *(const float2*)(xn + (size_t)c * 14400 + h * 900 + wi);
  }
#pragma unroll
  for (int s = 0; s < 4; ++s) {
    int e2 = t + 512 * s;
    int c = e2 >> 4, p = e2 & 15;
    int cl = 2 * p;
    u16 h0 = f2bf(xr[s].x), h1 = f2bf(xr[s].y);
    int ip = (c >> 4) * 640 + (p >> 2) * 160 + (c & 15) * 8 + (cl & 7);
    ushort2 pr; pr.x = h0; pr.y = h1;
    *(ushort2*)&xf[0][ip] = pr;
    int F = (p >> 3) * 4 + (c >> 5);
    int L = (((c >> 3) & 3) << 4) + (cl & 15);
    int i0 = F * 520 + L * 8 + (c & 7);
    xtf[0][i0] = h0;
    xtf[0][i0 + 8] = h1;
  }
#pragma unroll
  for (int s = 0; s < 4; ++s) {
    int e2 = t + 512 * s;
    int c = e2 >> 4, p = e2 & 15;
    int g = 32 + 2 * p;
    int h = g / 10, wi = g - 10 * h;
    xr[s] = *(const float2*)(xn + (size_t)c * 14400 + h * 900 + wi);
  }

  for (int cc = 0; cc < 5; ++cc) {
    const int cur = cc & 1;
    __syncthreads();                 // buf[cur] staging visible; prev P-mfma done

    // ---- logits MFMA: wave (colt, kt) computes 16 k-rows x 16 cols ----
    {
      float4v d0 = (float4v){0.f, 0.f, 0.f, 0.f};
#pragma unroll
      for (int cb32 = 0; cb32 < 4; ++cb32) {
        short8 xa = *(short8*)&xtf[cur][(colt * 4 + cb32) * 520 + lane * 8];
        d0 = __builtin_amdgcn_mfma_f32_16x16x32_bf16(xa, wh[cb32], d0, 0, 0, 0);
        d0 = __builtin_amdgcn_mfma_f32_16x16x32_bf16(xa, wl[cb32], d0, 0, 0, 0);
      }
      int colb = colt * 16 + ((lane >> 4) << 2);
#pragma unroll
      for (int r = 0; r < 4; ++r)
        As[kr * 33 + colb + r] = d0[r] + bk;
    }
    __syncthreads();

    // ---- wave-local softmax over k for cols [4*w8, 4*w8+4) ----
    {
      const int col4 = lane & 3;
      const int kq = lane >> 2;          // 16 groups of 4 k
      const int colg = w8 * 4 + col4;
      float m = -3.4e38f;
#pragma unroll
      for (int i = 0; i < 4; ++i) m = fmaxf(m, As[(kq * 4 + i) * 33 + colg]);
      m = fmaxf(m, __shfl_xor(m, 4));
      m = fmaxf(m, __shfl_xor(m, 8));
      m = fmaxf(m, __shfl_xor(m, 16));
      m = fmaxf(m, __shfl_xor(m, 32));
      float s = 0.f;
#pragma unroll
      for (int i = 0; i < 4; ++i) {
        int a = (kq * 4 + i) * 33 + colg;
        float e = __expf(As[a] - m);
        As[a] = e;
        s += e;
      }
      s += __shfl_xor(s, 4);
      s += __shfl_xor(s, 8);
      s += __shfl_xor(s, 16);
      s += __shfl_xor(s, 32);
      if (kq == 0) invs[colg] = 1.f / s;
    }
    // ---- a-frag build (same wave's columns, no barrier needed) ----
    {
      union { u16 u[4]; ushort4 v; } cvt;
      float paks = 0.f;
#pragma unroll
      for (int j = 0; j < 4; ++j) {
        float a = As[lane * 33 + w8 * 4 + j] * invs[w8 * 4 + j];
        paks += a;
        cvt.u[j] = f2bf(a);
      }
      pak += paks;
      int dst = ((lane >> 4) * 64 + ((w8 >> 1) << 4) + (lane & 15)) * 8 + (w8 & 1) * 4;
      *(ushort4*)&afr[dst] = cvt.v;
    }
    __syncthreads();

    // ---- P MFMA: wave (kt, w8&1) owns k-tile kt, 4 of 8 c-tiles;
    //      concurrently stage cc+1 into the idle buffer + issue cc+2 loads ----
    {
      short8 aa = *(short8*)&afr[((w8 >> 1) * 64 + lane) * 8];
#pragma unroll
      for (int c4 = 0; c4 < 4; ++c4) {
        int ct = (w8 & 1) * 4 + c4;
        short8 xb = *(short8*)&xf[cur][ct * 640 + (lane >> 4) * 160 + (lane & 15) * 8];
        pacc[c4] = __builtin_amdgcn_mfma_f32_16x16x32_bf16(aa, xb, pacc[c4], 0, 0, 0);
      }
    }
    if (cc < 4) {
      const int nxt = cur ^ 1;
#pragma unroll
      for (int s = 0; s < 4; ++s) {
        int e2 = t + 512 * s;
        int c = e2 >> 4, p = e2 & 15;
        int cl = 2 * p;
        u16 h0 = f2bf(xr[s].x), h1 = f2bf(xr[s].y);
        int ip = (c >> 4) * 640 + (p >> 2) * 160 + (c & 15) * 8 + (cl & 7);
        ushort2 pr; pr.x = h0; pr.y = h1;
        *(ushort2*)&xf[nxt][ip] = pr;
        int F = (p >> 3) * 4 + (c >> 5);
        int L = (((c >> 3) & 3) << 4) + (cl & 15);
        int i0 = F * 520 + L * 8 + (c & 7);
        xtf[nxt][i0] = h0;
        xtf[nxt][i0 + 8] = h1;
      }
      if (cc < 3) {
#pragma unroll
        for (int s = 0; s < 4; ++s) {
          int e2 = t + 512 * s;
          int c = e2 >> 4, p = e2 & 15;
          int g = (cc + 2) * 32 + 2 * p;
          int h = g / 10, wi = g - 10 * h;
          xr[s] = *(const float2*)(xn + (size_t)c * 14400 + h * 900 + wi);
        }
      }
    }
  }

  float* Pp = P + (size_t)(n * NCB + cb) * DDIM;
  {
    int krow = (w8 >> 1) * 16 + ((lane >> 4) << 2);
    int c0 = (w8 & 1) * 64 + (lane & 15);
#pragma unroll
    for (int c4 = 0; c4 < 4; ++c4)
#pragma unroll
      for (int r = 0; r < 4; ++r)
        Pp[(krow + r) * 128 + c0 + c4 * 16] = pacc[c4][r];
  }
  pasum[t] = pak;
  __syncthreads();
  if (t < 64) {
    float s = 0.f;
#pragma unroll
    for (int i = 0; i < 8; ++i) s += pasum[t + 64 * i];
    PA[(size_t)(n * NCB + cb) * 64 + t] = s;
  }
}

// ---------------------------------------------------------------------------
// K2: R5/R6/R7 form. Traffic- and TLP-insensitive; at its floor. Unchanged.
// ---------------------------------------------------------------------------
__global__ __launch_bounds__(256) void k2_vlad(
    const float* __restrict__ P, const float* __restrict__ PA,
    const float* __restrict__ centers, u16* __restrict__ vlad16,
    float* __restrict__ gss)            // [240][8]
{
  __shared__ float Ak[8];
  __shared__ float red[4];
  const int bx0 = blockIdx.x;                    // [0,1920)
  const int id = (bx0 & 7) * 240 + (bx0 >> 3);   // XCD pin: n = bx0&7
  const int n = id / 240;
  const int rem = id - n * 240;
  const int wt = rem >> 3, eb = rem & 7;
  const int win = n * NT + wt;
  const int t = threadIdx.x;

  if (t < 32) {
    int kk = t >> 2, ii = t & 3;
    float s = 0.f;
#pragma unroll
    for (int ss = 0; ss < 5; ++ss) {
      int i = ii + 4 * ss;
      int cb = (3 * wt + 80 + i) % 90;
      s += PA[((size_t)n * NCB + cb) * 64 + eb * 8 + kk];
    }
    s += __shfl_xor(s, 1);
    s += __shfl_xor(s, 2);
    if (ii == 0) Ak[kk] = s;
  }
  __syncthreads();

  const int e0 = eb * 1024 + t * 4;     // global (k,c) offset in [0,8192)
  const float* base = P + (size_t)n * NCB * DDIM + e0;
  float v[4];
#pragma unroll
  for (int j = 0; j < 4; ++j) v[j] = 0.f;
#pragma unroll 5
  for (int i = 0; i < 20; ++i) {
    int cb = (3 * wt + 80 + i) % 90;
    float4 u0 = *(const float4*)(base + (size_t)cb * DDIM);
    v[0] += u0.x; v[1] += u0.y; v[2] += u0.z; v[3] += u0.w;
  }

  const float A = Ak[t >> 5];           // k_local = t/32
  const float* ce = centers + e0;
  float ss8 = 0.f;
#pragma unroll
  for (int j = 0; j < 4; ++j) {
    float val = v[j] - ce[j] * A;
    v[j] = val;
    ss8 += val * val;
  }
  // per-k (32-thread group) reduction for intra-norm
  float ssg = ss8;
  ssg += __shfl_xor(ssg, 1);
  ssg += __shfl_xor(ssg, 2);
  ssg += __shfl_xor(ssg, 4);
  ssg += __shfl_xor(ssg, 8);
  ssg += __shfl_xor(ssg, 16);
  float rn = 1.f / fmaxf(sqrtf(ssg), EPSF);
  // block-wide sum of normalized squares (for global norm)
  float ts = ss8 * rn * rn;
  ts += __shfl_xor(ts, 1);
  ts += __shfl_xor(ts, 2);
  ts += __shfl_xor(ts, 4);
  ts += __shfl_xor(ts, 8);
  ts += __shfl_xor(ts, 16);
  ts += __shfl_xor(ts, 32);
  if ((t & 63) == 0) red[t >> 6] = ts;
  __syncthreads();
  if (t == 0) gss[(size_t)win * 8 + eb] = red[0] + red[1] + red[2] + red[3];

  union { u16 u[4]; ushort4 v4; } o;
#pragma unroll
  for (int j = 0; j < 4; ++j) o.u[j] = f2bf(v[j] * rn);
  *(ushort4*)(vlad16 + (size_t)win * DDIM + e0) = o.v4;
}

// ---------------------------------------------------------------------------
// K3 (MFMA): R6/R7 form (3 rt-tiles per block, XCD-pinned weight slices).
// Unchanged.
// ---------------------------------------------------------------------------
__global__ __launch_bounds__(256) void k3_gemm(
    const u16* __restrict__ vlad16, const float* __restrict__ gss,
    const float* __restrict__ mlp_w, float* __restrict__ part)
{
  __shared__ float ga[48];
  const int bx = blockIdx.x;         // [0,320)
  const int xcd = bx & 7;
  const int q = bx >> 3;             // [0,40)
  const int rtg = q % 5;             // rt-group: rows [rtg*48, rtg*48+48)
  const int h = (q / 5) * 8 + xcd;   // [0,64): same h -> same XCD, adjacent
  const int ot = h & 1;              // o half
  const int ks = h >> 1;             // K-slice of 256
  const int t = threadIdx.x;
  const int lane = t & 63;
  const int w = t >> 6;

  if (t < 48) {
    int r = rtg * 48 + t;
    float s = 0.f;
#pragma unroll
    for (int j = 0; j < 8; ++j) s += gss[(size_t)r * 8 + j];
    ga[t] = 1.f / fmaxf(sqrtf(s), EPSF);
  }
  __syncthreads();

  const int m = lane & 15;
  const int kg = lane >> 4;
  const int d0 = ks * 256 + kg * 8;
  const u16* a0 = vlad16 + (size_t)(rtg * 48 + m) * DDIM + d0;

  float4v acc[3][2];
#pragma unroll
  for (int mi = 0; mi < 3; ++mi)
#pragma unroll
    for (int i = 0; i < 2; ++i) acc[mi][i] = (float4v){0.f, 0.f, 0.f, 0.f};

#pragma unroll
  for (int ko = 0; ko < 8; ++ko) {
    short8 a[3];
#pragma unroll
    for (int mi = 0; mi < 3; ++mi)
      a[mi] = *(const short8*)(a0 + (size_t)(mi * 16) * DDIM + ko * 32);
#pragma unroll
    for (int nt = 0; nt < 2; ++nt) {
      int o = ot * 128 + w * 32 + nt * 16 + m;
      const float* wrow = mlp_w + (size_t)o * DDIM + d0 + ko * 32;
      float4 u0 = *(const float4*)wrow;
      float4 u1 = *(const float4*)(wrow + 4);
      union { u16 u[8]; short8 v; } bb;
      bb.u[0] = f2bf(u0.x); bb.u[1] = f2bf(u0.y); bb.u[2] = f2bf(u0.z); bb.u[3] = f2bf(u0.w);
      bb.u[4] = f2bf(u1.x); bb.u[5] = f2bf(u1.y); bb.u[6] = f2bf(u1.z); bb.u[7] = f2bf(u1.w);
#pragma unroll
      for (int mi = 0; mi < 3; ++mi)
        acc[mi][nt] = __builtin_amdgcn_mfma_f32_16x16x32_bf16(a[mi], bb.v, acc[mi][nt], 0, 0, 0);
    }
  }

  float* pp = part + ((size_t)ks * 240 + rtg * 48) * ODIM;
#pragma unroll
  for (int mi = 0; mi < 3; ++mi)
#pragma unroll
    for (int nt = 0; nt < 2; ++nt) {
      int o = ot * 128 + w * 32 + nt * 16 + m;
#pragma unroll
      for (int r = 0; r < 4; ++r) {
        int rl = mi * 16 + kg * 4 + r;
        pp[rl * ODIM + o] = acc[mi][nt][r] * ga[rl];
      }
    }
}

// ---------------------------------------------------------------------------
// K4: R5/R6/R7 form (1024 threads, 4-way split sum). At its floor. Unchanged.
// ---------------------------------------------------------------------------
__global__ __launch_bounds__(1024) void k4_out(
    const float* __restrict__ part, const float* __restrict__ bias,
    float* __restrict__ out)
{
  __shared__ float acc[4][256];
  __shared__ float red[4];
  const int r = blockIdx.x;
  const int t = threadIdx.x;
  const int o = t & 255, sq = t >> 8;

  float v = 0.f;
#pragma unroll
  for (int s = 0; s < 8; ++s)
    v += part[((size_t)(sq * 8 + s) * 240 + r) * ODIM + o];
  acc[sq][o] = v;
  __syncthreads();

  float ss = 0.f;
  if (t < 256) {
    v = acc[0][o] + acc[1][o] + acc[2][o] + acc[3][o] + bias[o];
    ss = v * v;
    ss += __shfl_xor(ss, 32);
    ss += __shfl_xor(ss, 16);
    ss += __shfl_xor(ss, 8);
    ss += __shfl_xor(ss, 4);
    ss += __shfl_xor(ss, 2);
    ss += __shfl_xor(ss, 1);
    if ((t & 63) == 0) red[t >> 6] = ss;
  }
  __syncthreads();
  if (t < 256) {
    float total = red[0] + red[1] + red[2] + red[3];
    out[(size_t)r * ODIM + o] = v / fmaxf(sqrtf(total), EPSF);
  }
}

// ---------------------------------------------------------------------------
extern "C" void kernel_launch(void* const* d_in, const int* in_sizes, int n_in,
                              void* d_out, int out_size, void* d_ws, size_t ws_size,
                              hipStream_t stream) {
  const float* x       = (const float*)d_in[0];
  const float* centers = (const float*)d_in[1];
  const float* conv_w  = (const float*)d_in[2];
  const float* conv_b  = (const float*)d_in[3];
  const float* mlp_w   = (const float*)d_in[4];
  const float* mlp_b   = (const float*)d_in[5];
  float* out = (float*)d_out;

  float* ws     = (float*)d_ws;
  float* P      = ws;                       // 5,898,240 floats (23.6 MB)
  float* PA     = ws + 5898240;             // 46,080 floats
  u16*   vlad16 = (u16*)(ws + 5944320);     // 240*8192 u16 (3.9 MB)
  float* gss    = (float*)(ws + 6927360);   // 240*8 floats
  float* part   = ws;                       // [32][240][256] overlays dead P

  k1_assign<<<dim3(8 * NCB),    dim3(512),  0, stream>>>(x, conv_w, conv_b, P, PA);
  k2_vlad  <<<dim3(8 * NT * 8), dim3(256),  0, stream>>>(P, PA, centers, vlad16, gss);
  k3_gemm  <<<dim3(320),        dim3(256),  0, stream>>>(vlad16, gss, mlp_w, part);
  k4_out   <<<dim3(240),        dim3(1024), 0, stream>>>(part, mlp_b, out);
}